// Round 13
// baseline (269.809 us; speedup 1.0000x reference)
//
#include <hip/hip_runtime.h>
#include <hip/hip_bf16.h>
#include <cstdint>

typedef unsigned short u16;
typedef unsigned int u32;
typedef __attribute__((ext_vector_type(4))) float f32x4;
typedef __attribute__((ext_vector_type(8))) __bf16 bf16x8;

#define NH 16
#define NKV 4
#define SEQ 2048
#define NTOK 4096

__device__ inline u16 f2bf(float f) {
  return __builtin_bit_cast(u16, __float2bfloat16(f));
}
__device__ inline float bf2f(u16 u) {
  return __bfloat162float(__builtin_bit_cast(__hip_bfloat16, u));
}

#define GLDS(gp, lp) __builtin_amdgcn_global_load_lds( \
    (__attribute__((address_space(1))) void*)(gp), \
    (__attribute__((address_space(3))) void*)(lp), 16, 0, 0)

#define VMCNT0 asm volatile("s_waitcnt vmcnt(0)" ::: "memory")

// ---------------- RMSNorm (f32 in, bf16 out) ----------------
__global__ __launch_bounds__(256) void rmsnorm_kernel(
    const float* __restrict__ x, const float* __restrict__ w,
    u16* __restrict__ out) {
  int row = blockIdx.x;
  int tid = threadIdx.x;
  const float4 v = reinterpret_cast<const float4*>(x + (size_t)row * 1024)[tid];
  float ss = v.x * v.x + v.y * v.y + v.z * v.z + v.w * v.w;
#pragma unroll
  for (int off = 32; off; off >>= 1) ss += __shfl_xor(ss, off);
  __shared__ float red[4];
  int lane = tid & 63, wid = tid >> 6;
  if (lane == 0) red[wid] = ss;
  __syncthreads();
  float tot = red[0] + red[1] + red[2] + red[3];
  float r = rsqrtf(tot * (1.0f / 1024.0f) + 1e-6f);
  const float4 wv = reinterpret_cast<const float4*>(w)[tid];
  ushort4 o;
  o.x = f2bf(v.x * r * wv.x);
  o.y = f2bf(v.y * r * wv.y);
  o.z = f2bf(v.z * r * wv.z);
  o.w = f2bf(v.w * r * wv.w);
  reinterpret_cast<ushort4*>(out + (size_t)row * 1024)[tid] = o;
}

// ---------------- weight transpose + cast: src[K][N] f32 -> dst[N][K] bf16 ----------------
__global__ __launch_bounds__(256) void transpose_cast_kernel(
    const float* __restrict__ src, u16* __restrict__ dst, int K, int N) {
  __shared__ float tile[32][33];
  int n0 = blockIdx.x * 32, k0 = blockIdx.y * 32;
  int tx = threadIdx.x & 31, ty = threadIdx.x >> 5;  // ty: 0..7
#pragma unroll
  for (int i = 0; i < 4; i++)
    tile[ty + i * 8][tx] = src[(size_t)(k0 + ty + i * 8) * N + n0 + tx];
  __syncthreads();
#pragma unroll
  for (int i = 0; i < 4; i++)
    dst[(size_t)(n0 + ty + i * 8) * K + k0 + tx] = f2bf(tile[tx][ty + i * 8]);
}

// Shared epilogue
template <int EP>
__device__ inline void epi_store(float v, size_t idx, int col,
                                 float* __restrict__ outf,
                                 const float* __restrict__ res,
                                 const float* __restrict__ scale,
                                 u16* __restrict__ outb) {
  if (EP == 0) {
    outf[idx] = v;
  } else if (EP == 1) {
    outf[idx] = res[idx] + v * scale[col];
  } else if (EP == 2) {
    outb[idx] = f2bf(v / (1.0f + __expf(-v)));
  } else {
    outb[idx] = f2bf(bf2f(outb[idx]) * v);
  }
}

// ---------------- gemmB: 128x128 tile, BK=64, 4 waves ----------------
template <int EP>
__global__ __launch_bounds__(256, 1) void gemmB(
    const u16* __restrict__ A, const u16* __restrict__ Bt,
    int M, int N, int K,
    float* __restrict__ outf, const float* __restrict__ res,
    const float* __restrict__ scale, u16* __restrict__ outb) {
  __shared__ u16 SA[2][128 * 64];
  __shared__ u16 SB[2][128 * 64];
  const int tid = threadIdx.x, lane = tid & 63, w = tid >> 6;  // 0..3
  const int wr = w >> 1, wc = w & 1;
  const int lg = lane >> 4, lc = lane & 15, cx = lc & 7;

  const int r8 = blockIdx.x & 7, j = blockIdx.x >> 3;
  const int bm = ((r8 << 2) + (j & 3)) << 7;   // M=4096: 32 m-blocks, 4 per XCD
  const int bn = (j >> 2) << 7;

  const int swrow = lane >> 3;
  const int swcol = (lane & 7) ^ swrow;
  const u16* gA = A + (size_t)(bm + w * 32 + swrow) * K + swcol * 8;
  const u16* gB = Bt + (size_t)(bn + w * 32 + swrow) * K + swcol * 8;

  const int NT = K >> 6;
  f32x4 acc[4][4] = {};

#define SG2(T_) do { int sl_ = (T_) & 1; size_t ko_ = (size_t)(T_) * 64; \
    GLDS(gA + ko_,                   &SA[sl_][(w * 32) * 64]); \
    GLDS(gA + ko_ + (size_t)8 * K,   &SA[sl_][(w * 32 + 8) * 64]); \
    GLDS(gA + ko_ + (size_t)16 * K,  &SA[sl_][(w * 32 + 16) * 64]); \
    GLDS(gA + ko_ + (size_t)24 * K,  &SA[sl_][(w * 32 + 24) * 64]); \
    GLDS(gB + ko_,                   &SB[sl_][(w * 32) * 64]); \
    GLDS(gB + ko_ + (size_t)8 * K,   &SB[sl_][(w * 32 + 8) * 64]); \
    GLDS(gB + ko_ + (size_t)16 * K,  &SB[sl_][(w * 32 + 16) * 64]); \
    GLDS(gB + ko_ + (size_t)24 * K,  &SB[sl_][(w * 32 + 24) * 64]); } while (0)

  SG2(0);
  VMCNT0;
  __builtin_amdgcn_s_barrier();

  for (int t = 0; t < NT; ++t) {
    const u16* sa = &SA[t & 1][0];
    const u16* sb = &SB[t & 1][0];
    const bool more = (t + 1 < NT);

    bf16x8 bfr[4][2], afr[4][2];
#pragma unroll
    for (int n = 0; n < 4; n++) {
      const int row = wc * 64 + n * 16 + lc;
#pragma unroll
      for (int ks = 0; ks < 2; ks++)
        bfr[n][ks] = *reinterpret_cast<const bf16x8*>(
            &sb[row * 64 + ((((ks << 2) | lg) ^ cx) << 3)]);
    }
#pragma unroll
    for (int i = 0; i < 4; i++) {
      const int row = wr * 64 + i * 16 + lc;
#pragma unroll
      for (int ks = 0; ks < 2; ks++)
        afr[i][ks] = *reinterpret_cast<const bf16x8*>(
            &sa[row * 64 + ((((ks << 2) | lg) ^ cx) << 3)]);
    }
    if (more) SG2(t + 1);
    __builtin_amdgcn_s_setprio(1);
#pragma unroll
    for (int i = 0; i < 4; i++)
#pragma unroll
      for (int n = 0; n < 4; n++) {
        acc[i][n] = __builtin_amdgcn_mfma_f32_16x16x32_bf16(afr[i][0], bfr[n][0], acc[i][n], 0, 0, 0);
        acc[i][n] = __builtin_amdgcn_mfma_f32_16x16x32_bf16(afr[i][1], bfr[n][1], acc[i][n], 0, 0, 0);
      }
    __builtin_amdgcn_s_setprio(0);
    VMCNT0;
    __builtin_amdgcn_s_barrier();
  }
#undef SG2

#pragma unroll
  for (int mi = 0; mi < 4; mi++)
#pragma unroll
    for (int ni = 0; ni < 4; ni++)
#pragma unroll
      for (int rg = 0; rg < 4; rg++) {
        const int row = bm + wr * 64 + mi * 16 + lg * 4 + rg;
        const int col = bn + wc * 64 + ni * 16 + lc;
        epi_store<EP>(acc[mi][ni][rg], (size_t)row * N + col, col, outf, res, scale, outb);
      }
}

// ---------------- fused gate+up GEMM v2: h = silu(xn@wg) * (xn@wu), bf16 out ----------------
// 128x128 tile, BK=64 (8-slot swizzle), 8 waves (2x4), wave = 64x32 out. LDS 96KB.
__global__ __launch_bounds__(512, 1) void gateup_kernel(
    const u16* __restrict__ A, const u16* __restrict__ Bg,
    const u16* __restrict__ Bu, u16* __restrict__ outb) {
  const int K = 1024, N = 4096;
  __shared__ u16 SA[2][128 * 64];
  __shared__ u16 SG[2][128 * 64];
  __shared__ u16 SU[2][128 * 64];
  const int tid = threadIdx.x, lane = tid & 63, w = tid >> 6;  // 8 waves
  const int wr = w >> 2, wc = w & 3;          // wave = 64 rows x 32 cols
  const int lg = lane >> 4, lc = lane & 15, cx = lc & 7;

  // bijective XCD map: 1024 blocks = 32 m-blocks x 32 n-blocks
  const int r8 = blockIdx.x & 7, j = blockIdx.x >> 3;  // j: 0..127
  const int bm = ((r8 >> 1) * 8 + (j & 7)) << 7;
  const int bn = ((r8 & 1) * 16 + (j >> 3)) << 7;

  // staging: proven gemmB pattern (rows of 128B, 8-chunk swizzle by row&7)
  const int swrow = lane >> 3;                  // 0..7
  const int swcol = (lane & 7) ^ swrow;         // pre-swizzled source chunk
  const u16* gAs = A + (size_t)(bm + w * 16 + swrow) * K + swcol * 8;
  const u16* gGs = Bg + (size_t)(bn + w * 16 + swrow) * K + swcol * 8;
  const u16* gUs = Bu + (size_t)(bn + w * 16 + swrow) * K + swcol * 8;

  f32x4 accG[4][2] = {}, accU[4][2] = {};

#define SGU(T_) do { int sl_ = (T_) & 1; size_t ko_ = (size_t)(T_) * 64; \
    GLDS(gAs + ko_,                  &SA[sl_][(w * 16) * 64]); \
    GLDS(gAs + ko_ + (size_t)8 * K,  &SA[sl_][(w * 16 + 8) * 64]); \
    GLDS(gGs + ko_,                  &SG[sl_][(w * 16) * 64]); \
    GLDS(gGs + ko_ + (size_t)8 * K,  &SG[sl_][(w * 16 + 8) * 64]); \
    GLDS(gUs + ko_,                  &SU[sl_][(w * 16) * 64]); \
    GLDS(gUs + ko_ + (size_t)8 * K,  &SU[sl_][(w * 16 + 8) * 64]); } while (0)

  SGU(0);
  VMCNT0;
  __builtin_amdgcn_s_barrier();

  for (int t = 0; t < 16; ++t) {
    const u16* sa = &SA[t & 1][0];
    const u16* sg = &SG[t & 1][0];
    const u16* su = &SU[t & 1][0];
    const bool more = (t + 1 < 16);

    bf16x8 afr[4][2], gfr[2][2], ufr[2][2];
#pragma unroll
    for (int i = 0; i < 4; i++) {
      const int row = wr * 64 + i * 16 + lc;
#pragma unroll
      for (int ks = 0; ks < 2; ks++)
        afr[i][ks] = *reinterpret_cast<const bf16x8*>(
            &sa[row * 64 + ((((ks << 2) | lg) ^ cx) << 3)]);
    }
#pragma unroll
    for (int n = 0; n < 2; n++) {
      const int row = wc * 32 + n * 16 + lc;
#pragma unroll
      for (int ks = 0; ks < 2; ks++) {
        const int off = row * 64 + ((((ks << 2) | lg) ^ cx) << 3);
        gfr[n][ks] = *reinterpret_cast<const bf16x8*>(&sg[off]);
        ufr[n][ks] = *reinterpret_cast<const bf16x8*>(&su[off]);
      }
    }
    if (more) SGU(t + 1);
    __builtin_amdgcn_s_setprio(1);
#pragma unroll
    for (int i = 0; i < 4; i++)
#pragma unroll
      for (int n = 0; n < 2; n++)
#pragma unroll
        for (int ks = 0; ks < 2; ks++) {
          accG[i][n] = __builtin_amdgcn_mfma_f32_16x16x32_bf16(afr[i][ks], gfr[n][ks], accG[i][n], 0, 0, 0);
          accU[i][n] = __builtin_amdgcn_mfma_f32_16x16x32_bf16(afr[i][ks], ufr[n][ks], accU[i][n], 0, 0, 0);
        }
    __builtin_amdgcn_s_setprio(0);
    VMCNT0;
    __builtin_amdgcn_s_barrier();
  }
#undef SGU

#pragma unroll
  for (int mi = 0; mi < 4; mi++)
#pragma unroll
    for (int ni = 0; ni < 2; ni++)
#pragma unroll
      for (int rg = 0; rg < 4; rg++) {
        const int row = bm + wr * 64 + mi * 16 + lg * 4 + rg;
        const int col = bn + wc * 32 + ni * 16 + lc;
        const float g = accG[mi][ni][rg];
        const float u = accU[mi][ni][rg];
        outb[(size_t)row * N + col] = f2bf((g / (1.0f + __expf(-g))) * u);
      }
}

// ---------------- RoPE: qkv f32 -> q_rope (pre-scaled by 0.125*log2e) bf16, k_rope bf16 ----------------
__global__ __launch_bounds__(256) void rope_kernel(
    const float* __restrict__ qkv, const float* __restrict__ cosb,
    const float* __restrict__ sinb, u16* __restrict__ qr, u16* __restrict__ kr) {
  int idx = blockIdx.x * 256 + threadIdx.x;  // B*S*20*32 total
  int d = idx & 31;
  int t = idx >> 5;
  int head = t % 20;
  int bs = t / 20;  // 0..4095
  int s = bs & (SEQ - 1);
  int b = bs >> 11;
  const float* row = qkv + (size_t)bs * 1536;
  float c = cosb[s * 32 + d], sn = sinb[s * 32 + d];
  const float QSC = 0.18033688011112042f;  // 0.125 * log2(e)
  float x1, x2;
  if (head < 16) {
    x1 = row[head * 64 + d];
    x2 = row[head * 64 + d + 32];
    size_t o = ((size_t)(b * NH + head) * SEQ + s) * 64 + d;
    qr[o] = f2bf((x1 * c + x2 * sn) * QSC);
    qr[o + 32] = f2bf((x2 * c - x1 * sn) * QSC);
  } else {
    int kh = head - 16;
    x1 = row[1024 + kh * 64 + d];
    x2 = row[1024 + kh * 64 + d + 32];
    size_t o = ((size_t)(b * NKV + kh) * SEQ + s) * 64 + d;
    kr[o] = f2bf(x1 * c + x2 * sn);
    kr[o + 32] = f2bf(x2 * c - x1 * sn);
  }
}

// ---------------- V transpose: qkv f32 -> vt [b][kv][d][s] bf16 ----------------
__global__ __launch_bounds__(256) void vtrans_kernel(
    const float* __restrict__ qkv, u16* __restrict__ vt) {
  int blk = blockIdx.x;
  int st = blk & 31; blk >>= 5;
  int kvh = blk & 3; blk >>= 2;
  int b = blk;
  __shared__ u16 tile[64][65];
  int tx = threadIdx.x & 63;
  int ty = threadIdx.x >> 6;  // 0..3
  int s0 = st * 64;
#pragma unroll
  for (int i = 0; i < 16; i++) {
    int sl = i * 4 + ty;
    tile[sl][tx] = f2bf(qkv[(size_t)(b * SEQ + s0 + sl) * 1536 + 1280 + kvh * 64 + tx]);
  }
  __syncthreads();
  size_t vbase = (size_t)(b * NKV + kvh) * 64 * SEQ;
#pragma unroll
  for (int i = 0; i < 16; i++) {
    int dd = i * 4 + ty;
    vt[vbase + (size_t)dd * SEQ + s0 + tx] = tile[tx][dd];
  }
}

// ---------------- Flash attention v4 (best measured): 8 waves, folded strips {j, 15-j} ----------------
__global__ __launch_bounds__(512, 1) void attn_kernel(
    const u16* __restrict__ qr, const u16* __restrict__ kr,
    const u16* __restrict__ vt, u16* __restrict__ out) {
  __shared__ u16 Ks[2][64 * 64];   // [key][d], swizzled
  __shared__ u16 Vs[2][64 * 64];   // [d][key], swizzled
  __shared__ u16 Ps[8][32 * 64];   // per-wave P[q][key], swizzled

  const int n = blockIdx.x;                 // 256 blocks
  const int g = n & 7;                      // b*4+kvh
  const int b = g >> 2, kvh = g & 3;
  const int h = kvh * 4 + ((n >> 3) & 3);
  const int j = n >> 5;                     // 0..7

  const int tid = threadIdx.x;
  const int lane = tid & 63, w = tid >> 6;  // 8 waves
  const int lg = lane >> 4, lc = lane & 15;
  const int lc7 = lc & 7;

  const int isH = (w ^ (w >> 2)) & 1;       // SIMD w&3 gets one light + one heavy
  const int strip = isH ? (15 - j) : j;     // 128-row q strip
  const int q0w = strip * 128 + (w >> 1) * 32;
  const int nt = 2 * (15 - j) + 2;          // tiles needed by heavy strip (18..32)

  bf16x8 qf[2][2];
  {
    const u16* qp = qr + ((size_t)(b * NH + h) * SEQ + q0w + lc) * 64 + lg * 8;
#pragma unroll
    for (int qt = 0; qt < 2; qt++) {
      qf[qt][0] = *reinterpret_cast<const bf16x8*>(qp + qt * 16 * 64);
      qf[qt][1] = *reinterpret_cast<const bf16x8*>(qp + qt * 16 * 64 + 32);
    }
  }
  VMCNT0;  // drain Q loads so in-loop vmcnt counting sees only GLDS

  const int srow = lane >> 3;                      // 0..7
  const int scw = ((lane & 7) ^ srow) << 3;        // pre-swizzled col (u16)
  const u16* ksrc = kr + (size_t)(b * NKV + kvh) * SEQ * 64 + (size_t)(w * 8 + srow) * 64 + scw;
  const u16* vsrc = vt + ((size_t)(b * NKV + kvh) * 64 + w * 8 + srow) * SEQ + scw;
  u16* Pw = &Ps[w][0];

#define STAGEA(bufi, t) do { \
    GLDS(ksrc + (size_t)(t) * 64 * 64, &Ks[bufi][(w * 8) * 64]); \
    GLDS(vsrc + (size_t)(t) * 64,      &Vs[bufi][(w * 8) * 64]); \
  } while (0)

  STAGEA(0, 0);

  float mm[2] = {-1e30f, -1e30f}, ll[2] = {0.0f, 0.0f};
  f32x4 oacc[2][4] = {};

  int buf = 0;
  for (int t = 0; t < nt; ++t) {
    if (t + 1 < nt) {
      STAGEA(buf ^ 1, t + 1);
      asm volatile("s_waitcnt vmcnt(2)" ::: "memory");
    } else {
      VMCNT0;
    }
    __builtin_amdgcn_s_barrier();
    __builtin_amdgcn_sched_barrier(0);

    const int c0 = t * 64;
    if (c0 <= q0w + 31) {
      bf16x8 kf[4][2];
#pragma unroll
      for (int ni = 0; ni < 4; ni++) {
        const int row = ni * 16 + lc;
#pragma unroll
        for (int hf = 0; hf < 2; hf++)
          kf[ni][hf] = *reinterpret_cast<const bf16x8*>(
              &Ks[buf][row * 64 + ((((hf * 64 + lg * 16)) ^ (lc7 << 4)) >> 1)]);
      }
      f32x4 sc[4][2] = {};
      __builtin_amdgcn_s_setprio(1);
#pragma unroll
      for (int ni = 0; ni < 4; ni++)
#pragma unroll
        for (int qt = 0; qt < 2; qt++) {
          sc[ni][qt] = __builtin_amdgcn_mfma_f32_16x16x32_bf16(kf[ni][0], qf[qt][0], sc[ni][qt], 0, 0, 0);
          sc[ni][qt] = __builtin_amdgcn_mfma_f32_16x16x32_bf16(kf[ni][1], qf[qt][1], sc[ni][qt], 0, 0, 0);
        }
      __builtin_amdgcn_s_setprio(0);
      bf16x8 vf[4][2];
#pragma unroll
      for (int dt = 0; dt < 4; dt++) {
        const int row = dt * 16 + lc;
#pragma unroll
        for (int ks = 0; ks < 2; ks++)
          vf[dt][ks] = *reinterpret_cast<const bf16x8*>(
              &Vs[buf][row * 64 + (((ks * 64 + lg * 16) ^ (lc7 << 4)) >> 1)]);
      }
      if (c0 + 63 > q0w) {
#pragma unroll
        for (int qt = 0; qt < 2; qt++) {
          const int q = q0w + qt * 16 + lc;
#pragma unroll
          for (int ni = 0; ni < 4; ni++)
#pragma unroll
            for (int rg = 0; rg < 4; rg++)
              if (c0 + ni * 16 + lg * 4 + rg > q) sc[ni][qt][rg] = -1e30f;
        }
      }
      float mx[2];
#pragma unroll
      for (int qt = 0; qt < 2; qt++) {
        float v = -1e30f;
#pragma unroll
        for (int ni = 0; ni < 4; ni++)
#pragma unroll
          for (int rg = 0; rg < 4; rg++) v = fmaxf(v, sc[ni][qt][rg]);
        v = fmaxf(v, __shfl_xor(v, 16));
        v = fmaxf(v, __shfl_xor(v, 32));
        mx[qt] = v;
      }
      if (!__all(mx[0] - mm[0] <= 11.5f && mx[1] - mm[1] <= 11.5f)) {
        float al[2];
#pragma unroll
        for (int qt = 0; qt < 2; qt++) {
          float mn = fmaxf(mm[qt], mx[qt]);
          al[qt] = exp2f(mm[qt] - mn);
          mm[qt] = mn;
          ll[qt] *= al[qt];
        }
#pragma unroll
        for (int qt = 0; qt < 2; qt++)
#pragma unroll
          for (int rg = 0; rg < 4; rg++) {
            float a = __shfl(al[qt], lg * 4 + rg);
#pragma unroll
            for (int dt = 0; dt < 4; dt++) oacc[qt][dt][rg] *= a;
          }
      }
#pragma unroll
      for (int qt = 0; qt < 2; qt++) {
        float rs = 0.0f;
#pragma unroll
        for (int ni = 0; ni < 4; ni++)
#pragma unroll
          for (int rg = 0; rg < 4; rg++) {
            float p = exp2f(sc[ni][qt][rg] - mm[qt]);
            sc[ni][qt][rg] = p;
            rs += p;
          }
        rs += __shfl_xor(rs, 16);
        rs += __shfl_xor(rs, 32);
        ll[qt] += rs;
      }
#pragma unroll
      for (int qt = 0; qt < 2; qt++)
#pragma unroll
        for (int ni = 0; ni < 4; ni++) {
          ushort4 pk;
          pk.x = f2bf(sc[ni][qt][0]);
          pk.y = f2bf(sc[ni][qt][1]);
          pk.z = f2bf(sc[ni][qt][2]);
          pk.w = f2bf(sc[ni][qt][3]);
          *reinterpret_cast<ushort4*>(
              &Pw[(qt * 16 + lc) * 64 + (((ni * 32 + lg * 8) ^ (lc7 << 4)) >> 1)]) = pk;
        }
      __builtin_amdgcn_s_setprio(1);
#pragma unroll
      for (int qt = 0; qt < 2; qt++)
#pragma unroll
        for (int ks = 0; ks < 2; ks++) {
          bf16x8 pa = *reinterpret_cast<const bf16x8*>(
              &Pw[(qt * 16 + lc) * 64 + (((ks * 64 + lg * 16) ^ (lc7 << 4)) >> 1)]);
#pragma unroll
          for (int dt = 0; dt < 4; dt++)
            oacc[qt][dt] = __builtin_amdgcn_mfma_f32_16x16x32_bf16(pa, vf[dt][ks], oacc[qt][dt], 0, 0, 0);
        }
      __builtin_amdgcn_s_setprio(0);
    }
    asm volatile("s_waitcnt lgkmcnt(0)" ::: "memory");
    __builtin_amdgcn_s_barrier();
    __builtin_amdgcn_sched_barrier(0);
    buf ^= 1;
  }
#undef STAGEA

#pragma unroll
  for (int qt = 0; qt < 2; qt++) {
    const float li = 1.0f / ll[qt];
#pragma unroll
    for (int rg = 0; rg < 4; rg++) {
      float liq = __shfl(li, lg * 4 + rg);
      int q = q0w + qt * 16 + lg * 4 + rg;
      u16* orow = out + (size_t)(b * SEQ + q) * 1024 + h * 64 + lc;
#pragma unroll
      for (int dt = 0; dt < 4; dt++)
        orow[dt * 16] = f2bf(oacc[qt][dt][rg] * liq);
    }
  }
}

extern "C" void kernel_launch(void* const* d_in, const int* in_sizes, int n_in,
                              void* d_out, int out_size, void* d_ws, size_t ws_size,
                              hipStream_t stream) {
  const float* x = (const float*)d_in[0];
  const float* w_norm1 = (const float*)d_in[1];
  const float* wq = (const float*)d_in[2];
  const float* wk = (const float*)d_in[3];
  const float* wv = (const float*)d_in[4];
  const float* wo = (const float*)d_in[5];
  const float* attn_scale = (const float*)d_in[6];
  const float* w_norm2 = (const float*)d_in[7];
  const float* wg = (const float*)d_in[8];
  const float* wu = (const float*)d_in[9];
  const float* wd = (const float*)d_in[10];
  const float* mlp_scale = (const float*)d_in[11];
  const float* cosb = (const float*)d_in[12];
  const float* sinb = (const float*)d_in[13];
  float* out = (float*)d_out;

  char* ws = (char*)d_ws;
  u16* wqkv_t = (u16*)(ws + 0);            // 1536x1024 bf16
  u16* wo_t = (u16*)(ws + 3145728);        // 1024x1024 bf16
  u16* wg_t = (u16*)(ws + 5242880);        // 4096x1024 bf16
  u16* wu_t = (u16*)(ws + 13631488);
  u16* wd_t = (u16*)(ws + 22020096);       // 1024x4096 bf16
  u16* xn = (u16*)(ws + 30408704);         // 4096x1024 bf16 (reused for xn2)
  float* qkv = (float*)(ws + 38797312);    // 4096x1536 f32
  u16* attn_o = (u16*)(ws + 38797312);     // alias (qkv dead)
  float* x1 = (float*)(ws + 47185920);     // 4096x1024 f32
  u16* q_rope = (u16*)(ws + 63963136);     // 2*16*2048*64 bf16
  u16* k_rope = (u16*)(ws + 72351744);     // 2*4*2048*64 bf16
  u16* vt = (u16*)(ws + 74448896);         // 2*4*64*2048 bf16
  u16* hbuf = (u16*)(ws + 63963136);       // alias (rope dead in FFN phase)

  dim3 tb(256);
  transpose_cast_kernel<<<dim3(32, 32), tb, 0, stream>>>(wq, wqkv_t, 1024, 1024);
  transpose_cast_kernel<<<dim3(8, 32), tb, 0, stream>>>(wk, wqkv_t + (size_t)1024 * 1024, 1024, 256);
  transpose_cast_kernel<<<dim3(8, 32), tb, 0, stream>>>(wv, wqkv_t + (size_t)1280 * 1024, 1024, 256);
  transpose_cast_kernel<<<dim3(32, 32), tb, 0, stream>>>(wo, wo_t, 1024, 1024);
  transpose_cast_kernel<<<dim3(128, 32), tb, 0, stream>>>(wg, wg_t, 1024, 4096);
  transpose_cast_kernel<<<dim3(128, 32), tb, 0, stream>>>(wu, wu_t, 1024, 4096);
  transpose_cast_kernel<<<dim3(32, 128), tb, 0, stream>>>(wd, wd_t, 4096, 1024);

  rmsnorm_kernel<<<4096, tb, 0, stream>>>(x, w_norm1, xn);
  gemmB<0><<<dim3(384), dim3(256), 0, stream>>>(xn, wqkv_t, 4096, 1536, 1024, qkv, nullptr, nullptr, nullptr);
  rope_kernel<<<10240, tb, 0, stream>>>(qkv, cosb, sinb, q_rope, k_rope);
  vtrans_kernel<<<2 * 4 * 32, tb, 0, stream>>>(qkv, vt);
  attn_kernel<<<256, dim3(512), 0, stream>>>(q_rope, k_rope, vt, attn_o);
  gemmB<1><<<dim3(256), dim3(256), 0, stream>>>(attn_o, wo_t, 4096, 1024, 1024, x1, x, attn_scale, nullptr);
  rmsnorm_kernel<<<4096, tb, 0, stream>>>(x1, w_norm2, xn);
  gateup_kernel<<<dim3(1024), dim3(512), 0, stream>>>(xn, wg_t, wu_t, hbuf);
  gemmB<1><<<dim3(256), dim3(256), 0, stream>>>(hbuf, wd_t, 4096, 1024, 4096, out, x1, mlp_scale, nullptr);
}

// Round 14
// 269.089 us; speedup vs baseline: 1.0027x; 1.0027x over previous
//
#include <hip/hip_runtime.h>
#include <hip/hip_bf16.h>
#include <cstdint>

typedef unsigned short u16;
typedef unsigned int u32;
typedef __attribute__((ext_vector_type(4))) float f32x4;
typedef __attribute__((ext_vector_type(8))) __bf16 bf16x8;

#define NH 16
#define NKV 4
#define SEQ 2048
#define NTOK 4096

__device__ inline u16 f2bf(float f) {
  return __builtin_bit_cast(u16, __float2bfloat16(f));
}
__device__ inline float bf2f(u16 u) {
  return __bfloat162float(__builtin_bit_cast(__hip_bfloat16, u));
}

#define GLDS(gp, lp) __builtin_amdgcn_global_load_lds( \
    (__attribute__((address_space(1))) void*)(gp), \
    (__attribute__((address_space(3))) void*)(lp), 16, 0, 0)

#define VMCNT0 asm volatile("s_waitcnt vmcnt(0)" ::: "memory")
#define VMCNT6 asm volatile("s_waitcnt vmcnt(6)" ::: "memory")

// ---------------- RMSNorm (f32 in, bf16 out) ----------------
__global__ __launch_bounds__(256) void rmsnorm_kernel(
    const float* __restrict__ x, const float* __restrict__ w,
    u16* __restrict__ out) {
  int row = blockIdx.x;
  int tid = threadIdx.x;
  const float4 v = reinterpret_cast<const float4*>(x + (size_t)row * 1024)[tid];
  float ss = v.x * v.x + v.y * v.y + v.z * v.z + v.w * v.w;
#pragma unroll
  for (int off = 32; off; off >>= 1) ss += __shfl_xor(ss, off);
  __shared__ float red[4];
  int lane = tid & 63, wid = tid >> 6;
  if (lane == 0) red[wid] = ss;
  __syncthreads();
  float tot = red[0] + red[1] + red[2] + red[3];
  float r = rsqrtf(tot * (1.0f / 1024.0f) + 1e-6f);
  const float4 wv = reinterpret_cast<const float4*>(w)[tid];
  ushort4 o;
  o.x = f2bf(v.x * r * wv.x);
  o.y = f2bf(v.y * r * wv.y);
  o.z = f2bf(v.z * r * wv.z);
  o.w = f2bf(v.w * r * wv.w);
  reinterpret_cast<ushort4*>(out + (size_t)row * 1024)[tid] = o;
}

// ---------------- weight transpose + cast: src[K][N] f32 -> dst[N][K] bf16 ----------------
__global__ __launch_bounds__(256) void transpose_cast_kernel(
    const float* __restrict__ src, u16* __restrict__ dst, int K, int N) {
  __shared__ float tile[32][33];
  int n0 = blockIdx.x * 32, k0 = blockIdx.y * 32;
  int tx = threadIdx.x & 31, ty = threadIdx.x >> 5;  // ty: 0..7
#pragma unroll
  for (int i = 0; i < 4; i++)
    tile[ty + i * 8][tx] = src[(size_t)(k0 + ty + i * 8) * N + n0 + tx];
  __syncthreads();
#pragma unroll
  for (int i = 0; i < 4; i++)
    dst[(size_t)(n0 + ty + i * 8) * K + k0 + tx] = f2bf(tile[tx][ty + i * 8]);
}

// Shared epilogue
template <int EP>
__device__ inline void epi_store(float v, size_t idx, int col,
                                 float* __restrict__ outf,
                                 const float* __restrict__ res,
                                 const float* __restrict__ scale,
                                 u16* __restrict__ outb) {
  if (EP == 0) {
    outf[idx] = v;
  } else if (EP == 1) {
    outf[idx] = res[idx] + v * scale[col];
  } else if (EP == 2) {
    outb[idx] = f2bf(v / (1.0f + __expf(-v)));
  } else {
    outb[idx] = f2bf(bf2f(outb[idx]) * v);
  }
}

// ---------------- gemmB: 128x128 tile, BK=64, 4 waves ----------------
template <int EP>
__global__ __launch_bounds__(256, 1) void gemmB(
    const u16* __restrict__ A, const u16* __restrict__ Bt,
    int M, int N, int K,
    float* __restrict__ outf, const float* __restrict__ res,
    const float* __restrict__ scale, u16* __restrict__ outb) {
  __shared__ u16 SA[2][128 * 64];
  __shared__ u16 SB[2][128 * 64];
  const int tid = threadIdx.x, lane = tid & 63, w = tid >> 6;  // 0..3
  const int wr = w >> 1, wc = w & 1;
  const int lg = lane >> 4, lc = lane & 15, cx = lc & 7;

  const int r8 = blockIdx.x & 7, j = blockIdx.x >> 3;
  const int bm = ((r8 << 2) + (j & 3)) << 7;   // M=4096: 32 m-blocks, 4 per XCD
  const int bn = (j >> 2) << 7;

  const int swrow = lane >> 3;
  const int swcol = (lane & 7) ^ swrow;
  const u16* gA = A + (size_t)(bm + w * 32 + swrow) * K + swcol * 8;
  const u16* gB = Bt + (size_t)(bn + w * 32 + swrow) * K + swcol * 8;

  const int NT = K >> 6;
  f32x4 acc[4][4] = {};

#define SG2(T_) do { int sl_ = (T_) & 1; size_t ko_ = (size_t)(T_) * 64; \
    GLDS(gA + ko_,                   &SA[sl_][(w * 32) * 64]); \
    GLDS(gA + ko_ + (size_t)8 * K,   &SA[sl_][(w * 32 + 8) * 64]); \
    GLDS(gA + ko_ + (size_t)16 * K,  &SA[sl_][(w * 32 + 16) * 64]); \
    GLDS(gA + ko_ + (size_t)24 * K,  &SA[sl_][(w * 32 + 24) * 64]); \
    GLDS(gB + ko_,                   &SB[sl_][(w * 32) * 64]); \
    GLDS(gB + ko_ + (size_t)8 * K,   &SB[sl_][(w * 32 + 8) * 64]); \
    GLDS(gB + ko_ + (size_t)16 * K,  &SB[sl_][(w * 32 + 16) * 64]); \
    GLDS(gB + ko_ + (size_t)24 * K,  &SB[sl_][(w * 32 + 24) * 64]); } while (0)

  SG2(0);
  VMCNT0;
  __builtin_amdgcn_s_barrier();

  for (int t = 0; t < NT; ++t) {
    const u16* sa = &SA[t & 1][0];
    const u16* sb = &SB[t & 1][0];
    const bool more = (t + 1 < NT);

    bf16x8 bfr[4][2], afr[4][2];
#pragma unroll
    for (int n = 0; n < 4; n++) {
      const int row = wc * 64 + n * 16 + lc;
#pragma unroll
      for (int ks = 0; ks < 2; ks++)
        bfr[n][ks] = *reinterpret_cast<const bf16x8*>(
            &sb[row * 64 + ((((ks << 2) | lg) ^ cx) << 3)]);
    }
#pragma unroll
    for (int i = 0; i < 4; i++) {
      const int row = wr * 64 + i * 16 + lc;
#pragma unroll
      for (int ks = 0; ks < 2; ks++)
        afr[i][ks] = *reinterpret_cast<const bf16x8*>(
            &sa[row * 64 + ((((ks << 2) | lg) ^ cx) << 3)]);
    }
    if (more) SG2(t + 1);
    __builtin_amdgcn_s_setprio(1);
#pragma unroll
    for (int i = 0; i < 4; i++)
#pragma unroll
      for (int n = 0; n < 4; n++) {
        acc[i][n] = __builtin_amdgcn_mfma_f32_16x16x32_bf16(afr[i][0], bfr[n][0], acc[i][n], 0, 0, 0);
        acc[i][n] = __builtin_amdgcn_mfma_f32_16x16x32_bf16(afr[i][1], bfr[n][1], acc[i][n], 0, 0, 0);
      }
    __builtin_amdgcn_s_setprio(0);
    VMCNT0;
    __builtin_amdgcn_s_barrier();
  }
#undef SG2

#pragma unroll
  for (int mi = 0; mi < 4; mi++)
#pragma unroll
    for (int ni = 0; ni < 4; ni++)
#pragma unroll
      for (int rg = 0; rg < 4; rg++) {
        const int row = bm + wr * 64 + mi * 16 + lg * 4 + rg;
        const int col = bn + wc * 64 + ni * 16 + lc;
        epi_store<EP>(acc[mi][ni][rg], (size_t)row * N + col, col, outf, res, scale, outb);
      }
}

// ---------------- fused gate+up GEMM v3: 8-phase counted-vmcnt pipeline (m201 schedule) ----------------
// BM=256, BN=128 out cols; B-panel = G(128 rows) | U(128 rows). LDS 128 KiB, 8 waves.
// Per K-tile: 4 phases x {ds_read quadrant | stage 1 half-tile | barrier | 16 MFMA | barrier}.
// vmcnt(6) once per K-tile (3 half-tiles in flight); stage lags consumption by 1 phase.
__global__ __launch_bounds__(512, 2) void gateup_kernel(
    const u16* __restrict__ A, const u16* __restrict__ Bg,
    const u16* __restrict__ Bu, u16* __restrict__ outb) {
  const int K = 1024, N = 4096, NT = 16;
  __shared__ u16 SA[2][256 * 64];
  __shared__ u16 SB[2][256 * 64];   // rows 0-127: G, rows 128-255: U
  const int tid = threadIdx.x, lane = tid & 63, w = tid >> 6;  // 8 waves
  const int wr = w >> 2, wc = w & 3;          // wave = 128 rows x 32 cols
  const int lg = lane >> 4, lc = lane & 15, cx = lc & 7;

  // bijective XCD map: 512 blocks = 16 m-blocks(256) x 32 n-blocks(128)
  const int r8 = blockIdx.x & 7, j = blockIdx.x >> 3;  // j: 0..63
  const int bm = (((r8 >> 1) << 2) + (j & 3)) << 8;
  const int bn = ((r8 & 1) * 16 + (j >> 2)) << 7;

  // staging bases (per-wave slices, source pre-swizzled by row&7)
  const int swrow = lane >> 3;                  // 0..7
  const int swcol = (lane & 7) ^ swrow;
  const u16* aA = A + (size_t)(bm + w * 8 + swrow) * K + swcol * 8;        // quadA rows
  const u16* aB = A + (size_t)(bm + 64 + w * 8 + swrow) * K + swcol * 8;   // quadB rows
  const u16* gG = Bg + (size_t)(bn + w * 16 + swrow) * K + swcol * 8;
  const u16* gU = Bu + (size_t)(bn + w * 16 + swrow) * K + swcol * 8;

  // half-tiles: h0 = A rows {0-63,128-191}; h3 = A rows {64-127,192-255};
  //             h1 = G -> SB rows 0-127;    h2 = U -> SB rows 128-255.
#define STAGE_H0(T_) do { int b_ = (T_) & 1; size_t ko_ = (size_t)(T_) * 64; \
    GLDS(aA + ko_,                  &SA[b_][(w * 8) * 64]); \
    GLDS(aA + ko_ + (size_t)128 * K, &SA[b_][(128 + w * 8) * 64]); } while (0)
#define STAGE_H3(T_) do { int b_ = (T_) & 1; size_t ko_ = (size_t)(T_) * 64; \
    GLDS(aB + ko_,                  &SA[b_][(64 + w * 8) * 64]); \
    GLDS(aB + ko_ + (size_t)128 * K, &SA[b_][(192 + w * 8) * 64]); } while (0)
#define STAGE_H1(T_) do { int b_ = (T_) & 1; size_t ko_ = (size_t)(T_) * 64; \
    GLDS(gG + ko_,                 &SB[b_][(w * 16) * 64]); \
    GLDS(gG + ko_ + (size_t)8 * K, &SB[b_][(w * 16 + 8) * 64]); } while (0)
#define STAGE_H2(T_) do { int b_ = (T_) & 1; size_t ko_ = (size_t)(T_) * 64; \
    GLDS(gU + ko_,                 &SB[b_][(128 + w * 16) * 64]); \
    GLDS(gU + ko_ + (size_t)8 * K, &SB[b_][(128 + w * 16 + 8) * 64]); } while (0)

  f32x4 accG[8][2] = {}, accU[8][2] = {};

  // prologue: tile0 complete + tile1 h0,h1,h2 -> vmcnt(6) guarantees tile0 resident
  STAGE_H0(0); STAGE_H1(0); STAGE_H2(0); STAGE_H3(0);
  STAGE_H0(1); STAGE_H1(1); STAGE_H2(1);
  VMCNT6;
  __builtin_amdgcn_s_barrier();

  for (int t = 0; t < NT; ++t) {
    const u16* sa = &SA[t & 1][0];
    const u16* sb = &SB[t & 1][0];
    bf16x8 afr[4][2], gfr[2][2], ufr[2][2];

    // ---- P0: G x m-quad0 ----
#pragma unroll
    for (int i = 0; i < 4; i++) {
      const int row = wr * 128 + i * 16 + lc;
#pragma unroll
      for (int ks = 0; ks < 2; ks++)
        afr[i][ks] = *reinterpret_cast<const bf16x8*>(
            &sa[row * 64 + ((((ks << 2) | lg) ^ cx) << 3)]);
    }
#pragma unroll
    for (int n = 0; n < 2; n++) {
      const int row = wc * 32 + n * 16 + lc;
#pragma unroll
      for (int ks = 0; ks < 2; ks++)
        gfr[n][ks] = *reinterpret_cast<const bf16x8*>(
            &sb[row * 64 + ((((ks << 2) | lg) ^ cx) << 3)]);
    }
    if (t + 1 < NT) STAGE_H3(t + 1);
    __builtin_amdgcn_s_barrier();
    __builtin_amdgcn_s_setprio(1);
#pragma unroll
    for (int i = 0; i < 4; i++)
#pragma unroll
      for (int n = 0; n < 2; n++)
#pragma unroll
        for (int ks = 0; ks < 2; ks++)
          accG[i][n] = __builtin_amdgcn_mfma_f32_16x16x32_bf16(afr[i][ks], gfr[n][ks], accG[i][n], 0, 0, 0);
    __builtin_amdgcn_s_setprio(0);
    __builtin_amdgcn_s_barrier();

    // ---- P1: U x m-quad0 ----
#pragma unroll
    for (int n = 0; n < 2; n++) {
      const int row = 128 + wc * 32 + n * 16 + lc;
#pragma unroll
      for (int ks = 0; ks < 2; ks++)
        ufr[n][ks] = *reinterpret_cast<const bf16x8*>(
            &sb[row * 64 + ((((ks << 2) | lg) ^ cx) << 3)]);
    }
    if (t + 2 < NT) STAGE_H0(t + 2);
    __builtin_amdgcn_s_barrier();
    __builtin_amdgcn_s_setprio(1);
#pragma unroll
    for (int i = 0; i < 4; i++)
#pragma unroll
      for (int n = 0; n < 2; n++)
#pragma unroll
        for (int ks = 0; ks < 2; ks++)
          accU[i][n] = __builtin_amdgcn_mfma_f32_16x16x32_bf16(afr[i][ks], ufr[n][ks], accU[i][n], 0, 0, 0);
    __builtin_amdgcn_s_setprio(0);
    __builtin_amdgcn_s_barrier();

    // ---- P2: G x m-quad1 ----
#pragma unroll
    for (int i = 0; i < 4; i++) {
      const int row = wr * 128 + 64 + i * 16 + lc;
#pragma unroll
      for (int ks = 0; ks < 2; ks++)
        afr[i][ks] = *reinterpret_cast<const bf16x8*>(
            &sa[row * 64 + ((((ks << 2) | lg) ^ cx) << 3)]);
    }
    if (t + 2 < NT) STAGE_H1(t + 2);
    __builtin_amdgcn_s_barrier();
    __builtin_amdgcn_s_setprio(1);
#pragma unroll
    for (int i = 0; i < 4; i++)
#pragma unroll
      for (int n = 0; n < 2; n++)
#pragma unroll
        for (int ks = 0; ks < 2; ks++)
          accG[4 + i][n] = __builtin_amdgcn_mfma_f32_16x16x32_bf16(afr[i][ks], gfr[n][ks], accG[4 + i][n], 0, 0, 0);
    __builtin_amdgcn_s_setprio(0);
    __builtin_amdgcn_s_barrier();

    // ---- P3: U x m-quad1 (K-tile checkpoint) ----
    if (t + 2 < NT) STAGE_H2(t + 2);
    if (t < NT - 3) { VMCNT6; } else { VMCNT0; }
    __builtin_amdgcn_s_barrier();
    __builtin_amdgcn_s_setprio(1);
#pragma unroll
    for (int i = 0; i < 4; i++)
#pragma unroll
      for (int n = 0; n < 2; n++)
#pragma unroll
        for (int ks = 0; ks < 2; ks++)
          accU[4 + i][n] = __builtin_amdgcn_mfma_f32_16x16x32_bf16(afr[i][ks], ufr[n][ks], accU[4 + i][n], 0, 0, 0);
    __builtin_amdgcn_s_setprio(0);
    __builtin_amdgcn_s_barrier();
  }
#undef STAGE_H0
#undef STAGE_H1
#undef STAGE_H2
#undef STAGE_H3

#pragma unroll
  for (int mi = 0; mi < 8; mi++)
#pragma unroll
    for (int ni = 0; ni < 2; ni++)
#pragma unroll
      for (int rg = 0; rg < 4; rg++) {
        const int row = bm + wr * 128 + ((mi < 4) ? mi * 16 : 64 + (mi - 4) * 16) + lg * 4 + rg;
        const int col = bn + wc * 32 + ni * 16 + lc;
        const float g = accG[mi][ni][rg];
        const float u = accU[mi][ni][rg];
        outb[(size_t)row * N + col] = f2bf((g / (1.0f + __expf(-g))) * u);
      }
}

// ---------------- RoPE: qkv f32 -> q_rope (pre-scaled by 0.125*log2e) bf16, k_rope bf16 ----------------
__global__ __launch_bounds__(256) void rope_kernel(
    const float* __restrict__ qkv, const float* __restrict__ cosb,
    const float* __restrict__ sinb, u16* __restrict__ qr, u16* __restrict__ kr) {
  int idx = blockIdx.x * 256 + threadIdx.x;  // B*S*20*32 total
  int d = idx & 31;
  int t = idx >> 5;
  int head = t % 20;
  int bs = t / 20;  // 0..4095
  int s = bs & (SEQ - 1);
  int b = bs >> 11;
  const float* row = qkv + (size_t)bs * 1536;
  float c = cosb[s * 32 + d], sn = sinb[s * 32 + d];
  const float QSC = 0.18033688011112042f;  // 0.125 * log2(e)
  float x1, x2;
  if (head < 16) {
    x1 = row[head * 64 + d];
    x2 = row[head * 64 + d + 32];
    size_t o = ((size_t)(b * NH + head) * SEQ + s) * 64 + d;
    qr[o] = f2bf((x1 * c + x2 * sn) * QSC);
    qr[o + 32] = f2bf((x2 * c - x1 * sn) * QSC);
  } else {
    int kh = head - 16;
    x1 = row[1024 + kh * 64 + d];
    x2 = row[1024 + kh * 64 + d + 32];
    size_t o = ((size_t)(b * NKV + kh) * SEQ + s) * 64 + d;
    kr[o] = f2bf(x1 * c + x2 * sn);
    kr[o + 32] = f2bf(x2 * c - x1 * sn);
  }
}

// ---------------- V transpose: qkv f32 -> vt [b][kv][d][s] bf16 ----------------
__global__ __launch_bounds__(256) void vtrans_kernel(
    const float* __restrict__ qkv, u16* __restrict__ vt) {
  int blk = blockIdx.x;
  int st = blk & 31; blk >>= 5;
  int kvh = blk & 3; blk >>= 2;
  int b = blk;
  __shared__ u16 tile[64][65];
  int tx = threadIdx.x & 63;
  int ty = threadIdx.x >> 6;  // 0..3
  int s0 = st * 64;
#pragma unroll
  for (int i = 0; i < 16; i++) {
    int sl = i * 4 + ty;
    tile[sl][tx] = f2bf(qkv[(size_t)(b * SEQ + s0 + sl) * 1536 + 1280 + kvh * 64 + tx]);
  }
  __syncthreads();
  size_t vbase = (size_t)(b * NKV + kvh) * 64 * SEQ;
#pragma unroll
  for (int i = 0; i < 16; i++) {
    int dd = i * 4 + ty;
    vt[vbase + (size_t)dd * SEQ + s0 + tx] = tile[tx][dd];
  }
}

// ---------------- Flash attention v4 (best measured): 8 waves, folded strips {j, 15-j} ----------------
__global__ __launch_bounds__(512, 1) void attn_kernel(
    const u16* __restrict__ qr, const u16* __restrict__ kr,
    const u16* __restrict__ vt, u16* __restrict__ out) {
  __shared__ u16 Ks[2][64 * 64];   // [key][d], swizzled
  __shared__ u16 Vs[2][64 * 64];   // [d][key], swizzled
  __shared__ u16 Ps[8][32 * 64];   // per-wave P[q][key], swizzled

  const int n = blockIdx.x;                 // 256 blocks
  const int g = n & 7;                      // b*4+kvh
  const int b = g >> 2, kvh = g & 3;
  const int h = kvh * 4 + ((n >> 3) & 3);
  const int j = n >> 5;                     // 0..7

  const int tid = threadIdx.x;
  const int lane = tid & 63, w = tid >> 6;  // 8 waves
  const int lg = lane >> 4, lc = lane & 15;
  const int lc7 = lc & 7;

  const int isH = (w ^ (w >> 2)) & 1;       // SIMD w&3 gets one light + one heavy
  const int strip = isH ? (15 - j) : j;     // 128-row q strip
  const int q0w = strip * 128 + (w >> 1) * 32;
  const int nt = 2 * (15 - j) + 2;          // tiles needed by heavy strip (18..32)

  bf16x8 qf[2][2];
  {
    const u16* qp = qr + ((size_t)(b * NH + h) * SEQ + q0w + lc) * 64 + lg * 8;
#pragma unroll
    for (int qt = 0; qt < 2; qt++) {
      qf[qt][0] = *reinterpret_cast<const bf16x8*>(qp + qt * 16 * 64);
      qf[qt][1] = *reinterpret_cast<const bf16x8*>(qp + qt * 16 * 64 + 32);
    }
  }
  VMCNT0;  // drain Q loads so in-loop vmcnt counting sees only GLDS

  const int srow = lane >> 3;                      // 0..7
  const int scw = ((lane & 7) ^ srow) << 3;        // pre-swizzled col (u16)
  const u16* ksrc = kr + (size_t)(b * NKV + kvh) * SEQ * 64 + (size_t)(w * 8 + srow) * 64 + scw;
  const u16* vsrc = vt + ((size_t)(b * NKV + kvh) * 64 + w * 8 + srow) * SEQ + scw;
  u16* Pw = &Ps[w][0];

#define STAGEA(bufi, t) do { \
    GLDS(ksrc + (size_t)(t) * 64 * 64, &Ks[bufi][(w * 8) * 64]); \
    GLDS(vsrc + (size_t)(t) * 64,      &Vs[bufi][(w * 8) * 64]); \
  } while (0)

  STAGEA(0, 0);

  float mm[2] = {-1e30f, -1e30f}, ll[2] = {0.0f, 0.0f};
  f32x4 oacc[2][4] = {};

  int buf = 0;
  for (int t = 0; t < nt; ++t) {
    if (t + 1 < nt) {
      STAGEA(buf ^ 1, t + 1);
      asm volatile("s_waitcnt vmcnt(2)" ::: "memory");
    } else {
      VMCNT0;
    }
    __builtin_amdgcn_s_barrier();
    __builtin_amdgcn_sched_barrier(0);

    const int c0 = t * 64;
    if (c0 <= q0w + 31) {
      bf16x8 kf[4][2];
#pragma unroll
      for (int ni = 0; ni < 4; ni++) {
        const int row = ni * 16 + lc;
#pragma unroll
        for (int hf = 0; hf < 2; hf++)
          kf[ni][hf] = *reinterpret_cast<const bf16x8*>(
              &Ks[buf][row * 64 + ((((hf * 64 + lg * 16)) ^ (lc7 << 4)) >> 1)]);
      }
      f32x4 sc[4][2] = {};
      __builtin_amdgcn_s_setprio(1);
#pragma unroll
      for (int ni = 0; ni < 4; ni++)
#pragma unroll
        for (int qt = 0; qt < 2; qt++) {
          sc[ni][qt] = __builtin_amdgcn_mfma_f32_16x16x32_bf16(kf[ni][0], qf[qt][0], sc[ni][qt], 0, 0, 0);
          sc[ni][qt] = __builtin_amdgcn_mfma_f32_16x16x32_bf16(kf[ni][1], qf[qt][1], sc[ni][qt], 0, 0, 0);
        }
      __builtin_amdgcn_s_setprio(0);
      bf16x8 vf[4][2];
#pragma unroll
      for (int dt = 0; dt < 4; dt++) {
        const int row = dt * 16 + lc;
#pragma unroll
        for (int ks = 0; ks < 2; ks++)
          vf[dt][ks] = *reinterpret_cast<const bf16x8*>(
              &Vs[buf][row * 64 + (((ks * 64 + lg * 16) ^ (lc7 << 4)) >> 1)]);
      }
      if (c0 + 63 > q0w) {
#pragma unroll
        for (int qt = 0; qt < 2; qt++) {
          const int q = q0w + qt * 16 + lc;
#pragma unroll
          for (int ni = 0; ni < 4; ni++)
#pragma unroll
            for (int rg = 0; rg < 4; rg++)
              if (c0 + ni * 16 + lg * 4 + rg > q) sc[ni][qt][rg] = -1e30f;
        }
      }
      float mx[2];
#pragma unroll
      for (int qt = 0; qt < 2; qt++) {
        float v = -1e30f;
#pragma unroll
        for (int ni = 0; ni < 4; ni++)
#pragma unroll
          for (int rg = 0; rg < 4; rg++) v = fmaxf(v, sc[ni][qt][rg]);
        v = fmaxf(v, __shfl_xor(v, 16));
        v = fmaxf(v, __shfl_xor(v, 32));
        mx[qt] = v;
      }
      if (!__all(mx[0] - mm[0] <= 11.5f && mx[1] - mm[1] <= 11.5f)) {
        float al[2];
#pragma unroll
        for (int qt = 0; qt < 2; qt++) {
          float mn = fmaxf(mm[qt], mx[qt]);
          al[qt] = exp2f(mm[qt] - mn);
          mm[qt] = mn;
          ll[qt] *= al[qt];
        }
#pragma unroll
        for (int qt = 0; qt < 2; qt++)
#pragma unroll
          for (int rg = 0; rg < 4; rg++) {
            float a = __shfl(al[qt], lg * 4 + rg);
#pragma unroll
            for (int dt = 0; dt < 4; dt++) oacc[qt][dt][rg] *= a;
          }
      }
#pragma unroll
      for (int qt = 0; qt < 2; qt++) {
        float rs = 0.0f;
#pragma unroll
        for (int ni = 0; ni < 4; ni++)
#pragma unroll
          for (int rg = 0; rg < 4; rg++) {
            float p = exp2f(sc[ni][qt][rg] - mm[qt]);
            sc[ni][qt][rg] = p;
            rs += p;
          }
        rs += __shfl_xor(rs, 16);
        rs += __shfl_xor(rs, 32);
        ll[qt] += rs;
      }
#pragma unroll
      for (int qt = 0; qt < 2; qt++)
#pragma unroll
        for (int ni = 0; ni < 4; ni++) {
          ushort4 pk;
          pk.x = f2bf(sc[ni][qt][0]);
          pk.y = f2bf(sc[ni][qt][1]);
          pk.z = f2bf(sc[ni][qt][2]);
          pk.w = f2bf(sc[ni][qt][3]);
          *reinterpret_cast<ushort4*>(
              &Pw[(qt * 16 + lc) * 64 + (((ni * 32 + lg * 8) ^ (lc7 << 4)) >> 1)]) = pk;
        }
      __builtin_amdgcn_s_setprio(1);
#pragma unroll
      for (int qt = 0; qt < 2; qt++)
#pragma unroll
        for (int ks = 0; ks < 2; ks++) {
          bf16x8 pa = *reinterpret_cast<const bf16x8*>(
              &Pw[(qt * 16 + lc) * 64 + (((ks * 64 + lg * 16) ^ (lc7 << 4)) >> 1)]);
#pragma unroll
          for (int dt = 0; dt < 4; dt++)
            oacc[qt][dt] = __builtin_amdgcn_mfma_f32_16x16x32_bf16(pa, vf[dt][ks], oacc[qt][dt], 0, 0, 0);
        }
      __builtin_amdgcn_s_setprio(0);
    }
    asm volatile("s_waitcnt lgkmcnt(0)" ::: "memory");
    __builtin_amdgcn_s_barrier();
    __builtin_amdgcn_sched_barrier(0);
    buf ^= 1;
  }
#undef STAGEA

#pragma unroll
  for (int qt = 0; qt < 2; qt++) {
    const float li = 1.0f / ll[qt];
#pragma unroll
    for (int rg = 0; rg < 4; rg++) {
      float liq = __shfl(li, lg * 4 + rg);
      int q = q0w + qt * 16 + lg * 4 + rg;
      u16* orow = out + (size_t)(b * SEQ + q) * 1024 + h * 64 + lc;
#pragma unroll
      for (int dt = 0; dt < 4; dt++)
        orow[dt * 16] = f2bf(oacc[qt][dt][rg] * liq);
    }
  }
}

extern "C" void kernel_launch(void* const* d_in, const int* in_sizes, int n_in,
                              void* d_out, int out_size, void* d_ws, size_t ws_size,
                              hipStream_t stream) {
  const float* x = (const float*)d_in[0];
  const float* w_norm1 = (const float*)d_in[1];
  const float* wq = (const float*)d_in[2];
  const float* wk = (const float*)d_in[3];
  const float* wv = (const float*)d_in[4];
  const float* wo = (const float*)d_in[5];
  const float* attn_scale = (const float*)d_in[6];
  const float* w_norm2 = (const float*)d_in[7];
  const float* wg = (const float*)d_in[8];
  const float* wu = (const float*)d_in[9];
  const float* wd = (const float*)d_in[10];
  const float* mlp_scale = (const float*)d_in[11];
  const float* cosb = (const float*)d_in[12];
  const float* sinb = (const float*)d_in[13];
  float* out = (float*)d_out;

  char* ws = (char*)d_ws;
  u16* wqkv_t = (u16*)(ws + 0);            // 1536x1024 bf16
  u16* wo_t = (u16*)(ws + 3145728);        // 1024x1024 bf16
  u16* wg_t = (u16*)(ws + 5242880);        // 4096x1024 bf16
  u16* wu_t = (u16*)(ws + 13631488);
  u16* wd_t = (u16*)(ws + 22020096);       // 1024x4096 bf16
  u16* xn = (u16*)(ws + 30408704);         // 4096x1024 bf16 (reused for xn2)
  float* qkv = (float*)(ws + 38797312);    // 4096x1536 f32
  u16* attn_o = (u16*)(ws + 38797312);     // alias (qkv dead)
  float* x1 = (float*)(ws + 47185920);     // 4096x1024 f32
  u16* q_rope = (u16*)(ws + 63963136);     // 2*16*2048*64 bf16
  u16* k_rope = (u16*)(ws + 72351744);     // 2*4*2048*64 bf16
  u16* vt = (u16*)(ws + 74448896);         // 2*4*64*2048 bf16
  u16* hbuf = (u16*)(ws + 63963136);       // alias (rope dead in FFN phase)

  dim3 tb(256);
  transpose_cast_kernel<<<dim3(32, 32), tb, 0, stream>>>(wq, wqkv_t, 1024, 1024);
  transpose_cast_kernel<<<dim3(8, 32), tb, 0, stream>>>(wk, wqkv_t + (size_t)1024 * 1024, 1024, 256);
  transpose_cast_kernel<<<dim3(8, 32), tb, 0, stream>>>(wv, wqkv_t + (size_t)1280 * 1024, 1024, 256);
  transpose_cast_kernel<<<dim3(32, 32), tb, 0, stream>>>(wo, wo_t, 1024, 1024);
  transpose_cast_kernel<<<dim3(128, 32), tb, 0, stream>>>(wg, wg_t, 1024, 4096);
  transpose_cast_kernel<<<dim3(128, 32), tb, 0, stream>>>(wu, wu_t, 1024, 4096);
  transpose_cast_kernel<<<dim3(32, 128), tb, 0, stream>>>(wd, wd_t, 4096, 1024);

  rmsnorm_kernel<<<4096, tb, 0, stream>>>(x, w_norm1, xn);
  gemmB<0><<<dim3(384), dim3(256), 0, stream>>>(xn, wqkv_t, 4096, 1536, 1024, qkv, nullptr, nullptr, nullptr);
  rope_kernel<<<10240, tb, 0, stream>>>(qkv, cosb, sinb, q_rope, k_rope);
  vtrans_kernel<<<2 * 4 * 32, tb, 0, stream>>>(qkv, vt);
  attn_kernel<<<256, dim3(512), 0, stream>>>(q_rope, k_rope, vt, attn_o);
  gemmB<1><<<dim3(256), dim3(256), 0, stream>>>(attn_o, wo_t, 4096, 1024, 1024, x1, x, attn_scale, nullptr);
  rmsnorm_kernel<<<4096, tb, 0, stream>>>(x1, w_norm2, xn);
  gateup_kernel<<<dim3(512), dim3(512), 0, stream>>>(xn, wg_t, wu_t, hbuf);
  gemmB<1><<<dim3(256), dim3(256), 0, stream>>>(hbuf, wd_t, 4096, 1024, 4096, out, x1, mlp_scale, nullptr);
}

// Round 15
// 267.258 us; speedup vs baseline: 1.0095x; 1.0069x over previous
//
#include <hip/hip_runtime.h>
#include <hip/hip_bf16.h>
#include <cstdint>

typedef unsigned short u16;
typedef unsigned int u32;
typedef __attribute__((ext_vector_type(4))) float f32x4;
typedef __attribute__((ext_vector_type(8))) __bf16 bf16x8;

#define NH 16
#define NKV 4
#define SEQ 2048
#define NTOK 4096

__device__ inline u16 f2bf(float f) {
  return __builtin_bit_cast(u16, __float2bfloat16(f));
}
__device__ inline float bf2f(u16 u) {
  return __bfloat162float(__builtin_bit_cast(__hip_bfloat16, u));
}

#define GLDS(gp, lp) __builtin_amdgcn_global_load_lds( \
    (__attribute__((address_space(1))) void*)(gp), \
    (__attribute__((address_space(3))) void*)(lp), 16, 0, 0)

#define VMCNT0 asm volatile("s_waitcnt vmcnt(0)" ::: "memory")

// ---------------- RMSNorm (f32 in, bf16 out) ----------------
__global__ __launch_bounds__(256) void rmsnorm_kernel(
    const float* __restrict__ x, const float* __restrict__ w,
    u16* __restrict__ out) {
  int row = blockIdx.x;
  int tid = threadIdx.x;
  const float4 v = reinterpret_cast<const float4*>(x + (size_t)row * 1024)[tid];
  float ss = v.x * v.x + v.y * v.y + v.z * v.z + v.w * v.w;
#pragma unroll
  for (int off = 32; off; off >>= 1) ss += __shfl_xor(ss, off);
  __shared__ float red[4];
  int lane = tid & 63, wid = tid >> 6;
  if (lane == 0) red[wid] = ss;
  __syncthreads();
  float tot = red[0] + red[1] + red[2] + red[3];
  float r = rsqrtf(tot * (1.0f / 1024.0f) + 1e-6f);
  const float4 wv = reinterpret_cast<const float4*>(w)[tid];
  ushort4 o;
  o.x = f2bf(v.x * r * wv.x);
  o.y = f2bf(v.y * r * wv.y);
  o.z = f2bf(v.z * r * wv.z);
  o.w = f2bf(v.w * r * wv.w);
  reinterpret_cast<ushort4*>(out + (size_t)row * 1024)[tid] = o;
}

// ---------------- weight transpose + cast: src[K][N] f32 -> dst[N][K] bf16 ----------------
__global__ __launch_bounds__(256) void transpose_cast_kernel(
    const float* __restrict__ src, u16* __restrict__ dst, int K, int N) {
  __shared__ float tile[32][33];
  int n0 = blockIdx.x * 32, k0 = blockIdx.y * 32;
  int tx = threadIdx.x & 31, ty = threadIdx.x >> 5;  // ty: 0..7
#pragma unroll
  for (int i = 0; i < 4; i++)
    tile[ty + i * 8][tx] = src[(size_t)(k0 + ty + i * 8) * N + n0 + tx];
  __syncthreads();
#pragma unroll
  for (int i = 0; i < 4; i++)
    dst[(size_t)(n0 + ty + i * 8) * K + k0 + tx] = f2bf(tile[tx][ty + i * 8]);
}

// Shared epilogue
template <int EP>
__device__ inline void epi_store(float v, size_t idx, int col,
                                 float* __restrict__ outf,
                                 const float* __restrict__ res,
                                 const float* __restrict__ scale,
                                 u16* __restrict__ outb) {
  if (EP == 0) {
    outf[idx] = v;
  } else if (EP == 1) {
    outf[idx] = res[idx] + v * scale[col];
  } else if (EP == 2) {
    outb[idx] = f2bf(v / (1.0f + __expf(-v)));
  } else {
    outb[idx] = f2bf(bf2f(outb[idx]) * v);
  }
}

// ---------------- gemmB: 128x128 tile, BK=64, 4 waves ----------------
template <int EP>
__global__ __launch_bounds__(256, 1) void gemmB(
    const u16* __restrict__ A, const u16* __restrict__ Bt,
    int M, int N, int K,
    float* __restrict__ outf, const float* __restrict__ res,
    const float* __restrict__ scale, u16* __restrict__ outb) {
  __shared__ u16 SA[2][128 * 64];
  __shared__ u16 SB[2][128 * 64];
  const int tid = threadIdx.x, lane = tid & 63, w = tid >> 6;  // 0..3
  const int wr = w >> 1, wc = w & 1;
  const int lg = lane >> 4, lc = lane & 15, cx = lc & 7;

  const int r8 = blockIdx.x & 7, j = blockIdx.x >> 3;
  const int bm = ((r8 << 2) + (j & 3)) << 7;   // M=4096: 32 m-blocks, 4 per XCD
  const int bn = (j >> 2) << 7;

  const int swrow = lane >> 3;
  const int swcol = (lane & 7) ^ swrow;
  const u16* gA = A + (size_t)(bm + w * 32 + swrow) * K + swcol * 8;
  const u16* gB = Bt + (size_t)(bn + w * 32 + swrow) * K + swcol * 8;

  const int NT = K >> 6;
  f32x4 acc[4][4] = {};

#define SG2(T_) do { int sl_ = (T_) & 1; size_t ko_ = (size_t)(T_) * 64; \
    GLDS(gA + ko_,                   &SA[sl_][(w * 32) * 64]); \
    GLDS(gA + ko_ + (size_t)8 * K,   &SA[sl_][(w * 32 + 8) * 64]); \
    GLDS(gA + ko_ + (size_t)16 * K,  &SA[sl_][(w * 32 + 16) * 64]); \
    GLDS(gA + ko_ + (size_t)24 * K,  &SA[sl_][(w * 32 + 24) * 64]); \
    GLDS(gB + ko_,                   &SB[sl_][(w * 32) * 64]); \
    GLDS(gB + ko_ + (size_t)8 * K,   &SB[sl_][(w * 32 + 8) * 64]); \
    GLDS(gB + ko_ + (size_t)16 * K,  &SB[sl_][(w * 32 + 16) * 64]); \
    GLDS(gB + ko_ + (size_t)24 * K,  &SB[sl_][(w * 32 + 24) * 64]); } while (0)

  SG2(0);
  VMCNT0;
  __builtin_amdgcn_s_barrier();

  for (int t = 0; t < NT; ++t) {
    const u16* sa = &SA[t & 1][0];
    const u16* sb = &SB[t & 1][0];
    const bool more = (t + 1 < NT);

    bf16x8 bfr[4][2], afr[4][2];
#pragma unroll
    for (int n = 0; n < 4; n++) {
      const int row = wc * 64 + n * 16 + lc;
#pragma unroll
      for (int ks = 0; ks < 2; ks++)
        bfr[n][ks] = *reinterpret_cast<const bf16x8*>(
            &sb[row * 64 + ((((ks << 2) | lg) ^ cx) << 3)]);
    }
#pragma unroll
    for (int i = 0; i < 4; i++) {
      const int row = wr * 64 + i * 16 + lc;
#pragma unroll
      for (int ks = 0; ks < 2; ks++)
        afr[i][ks] = *reinterpret_cast<const bf16x8*>(
            &sa[row * 64 + ((((ks << 2) | lg) ^ cx) << 3)]);
    }
    if (more) SG2(t + 1);
    __builtin_amdgcn_s_setprio(1);
#pragma unroll
    for (int i = 0; i < 4; i++)
#pragma unroll
      for (int n = 0; n < 4; n++) {
        acc[i][n] = __builtin_amdgcn_mfma_f32_16x16x32_bf16(afr[i][0], bfr[n][0], acc[i][n], 0, 0, 0);
        acc[i][n] = __builtin_amdgcn_mfma_f32_16x16x32_bf16(afr[i][1], bfr[n][1], acc[i][n], 0, 0, 0);
      }
    __builtin_amdgcn_s_setprio(0);
    VMCNT0;
    __builtin_amdgcn_s_barrier();
  }
#undef SG2

#pragma unroll
  for (int mi = 0; mi < 4; mi++)
#pragma unroll
    for (int ni = 0; ni < 4; ni++)
#pragma unroll
      for (int rg = 0; rg < 4; rg++) {
        const int row = bm + wr * 64 + mi * 16 + lg * 4 + rg;
        const int col = bn + wc * 64 + ni * 16 + lc;
        epi_store<EP>(acc[mi][ni][rg], (size_t)row * N + col, col, outf, res, scale, outb);
      }
}

// ---------------- QKV GEMM with fused RoPE + V-transpose epilogue ----------------
// gemmB engine (128x128, BK=64, 4 waves). N=1536: n-blocks 0-7 Q, 8-9 K, 10-11 V.
// Each 64-col wave half is head-aligned; rope pair (d, d+32) = acc[.][ni]/acc[.][ni+2].
__global__ __launch_bounds__(256, 1) void qkvrope_kernel(
    const u16* __restrict__ A, const u16* __restrict__ Bt,
    const float* __restrict__ cosb, const float* __restrict__ sinb,
    u16* __restrict__ qr, u16* __restrict__ kr, u16* __restrict__ vt) {
  const int N = 1536, K = 1024, NT = 16;
  __shared__ u16 SA[2][128 * 64];
  __shared__ u16 SB[2][128 * 64];
  __shared__ u16 TT[4][64 * 66];
  const int tid = threadIdx.x, lane = tid & 63, w = tid >> 6;
  const int wr = w >> 1, wc = w & 1;
  const int lg = lane >> 4, lc = lane & 15, cx = lc & 7;

  // 384 blocks = 32 m-blocks x 12 n-blocks, XCD digit on m
  const int r8 = blockIdx.x & 7, j = blockIdx.x >> 3;  // j: 0..47
  const int bm = ((r8 << 2) + (j & 3)) << 7;
  const int bn = (j >> 2) << 7;

  const int swrow = lane >> 3;
  const int swcol = (lane & 7) ^ swrow;
  const u16* gA = A + (size_t)(bm + w * 32 + swrow) * K + swcol * 8;
  const u16* gB = Bt + (size_t)(bn + w * 32 + swrow) * K + swcol * 8;

  f32x4 acc[4][4] = {};

#define SG2(T_) do { int sl_ = (T_) & 1; size_t ko_ = (size_t)(T_) * 64; \
    GLDS(gA + ko_,                   &SA[sl_][(w * 32) * 64]); \
    GLDS(gA + ko_ + (size_t)8 * K,   &SA[sl_][(w * 32 + 8) * 64]); \
    GLDS(gA + ko_ + (size_t)16 * K,  &SA[sl_][(w * 32 + 16) * 64]); \
    GLDS(gA + ko_ + (size_t)24 * K,  &SA[sl_][(w * 32 + 24) * 64]); \
    GLDS(gB + ko_,                   &SB[sl_][(w * 32) * 64]); \
    GLDS(gB + ko_ + (size_t)8 * K,   &SB[sl_][(w * 32 + 8) * 64]); \
    GLDS(gB + ko_ + (size_t)16 * K,  &SB[sl_][(w * 32 + 16) * 64]); \
    GLDS(gB + ko_ + (size_t)24 * K,  &SB[sl_][(w * 32 + 24) * 64]); } while (0)

  SG2(0);
  VMCNT0;
  __builtin_amdgcn_s_barrier();

  for (int t = 0; t < NT; ++t) {
    const u16* sa = &SA[t & 1][0];
    const u16* sb = &SB[t & 1][0];
    const bool more = (t + 1 < NT);

    bf16x8 bfr[4][2], afr[4][2];
#pragma unroll
    for (int n = 0; n < 4; n++) {
      const int row = wc * 64 + n * 16 + lc;
#pragma unroll
      for (int ks = 0; ks < 2; ks++)
        bfr[n][ks] = *reinterpret_cast<const bf16x8*>(
            &sb[row * 64 + ((((ks << 2) | lg) ^ cx) << 3)]);
    }
#pragma unroll
    for (int i = 0; i < 4; i++) {
      const int row = wr * 64 + i * 16 + lc;
#pragma unroll
      for (int ks = 0; ks < 2; ks++)
        afr[i][ks] = *reinterpret_cast<const bf16x8*>(
            &sa[row * 64 + ((((ks << 2) | lg) ^ cx) << 3)]);
    }
    if (more) SG2(t + 1);
    __builtin_amdgcn_s_setprio(1);
#pragma unroll
    for (int i = 0; i < 4; i++)
#pragma unroll
      for (int n = 0; n < 4; n++) {
        acc[i][n] = __builtin_amdgcn_mfma_f32_16x16x32_bf16(afr[i][0], bfr[n][0], acc[i][n], 0, 0, 0);
        acc[i][n] = __builtin_amdgcn_mfma_f32_16x16x32_bf16(afr[i][1], bfr[n][1], acc[i][n], 0, 0, 0);
      }
    __builtin_amdgcn_s_setprio(0);
    VMCNT0;
    __builtin_amdgcn_s_barrier();
  }
#undef SG2

  const int colbase = bn + wc * 64;
  const int hh = colbase >> 6;  // 0..23
  const float QSC = 0.18033688011112042f;  // 0.125 * log2(e)

  if (hh < 20) {
    // Q (rope, scaled) or K (rope, unscaled)
    const bool isQ = (hh < 16);
    const int head = isQ ? hh : hh - 16;
    u16* dst = isQ ? qr : kr;
    const int hstride = isQ ? NH : NKV;
    const float scq = isQ ? QSC : 1.0f;
#pragma unroll
    for (int mi = 0; mi < 4; mi++)
#pragma unroll
      for (int rg = 0; rg < 4; rg++) {
        const int row = bm + wr * 64 + mi * 16 + lg * 4 + rg;
        const int s = row & (SEQ - 1), b = row >> 11;
        u16* obase = dst + ((size_t)(b * hstride + head) * SEQ + s) * 64;
#pragma unroll
        for (int ni = 0; ni < 2; ni++) {
          const int d = ni * 16 + lc;
          const float c = cosb[s * 32 + d];
          const float sn = sinb[s * 32 + d];
          const float x1 = acc[mi][ni][rg];
          const float x2 = acc[mi][ni + 2][rg];
          obase[d] = f2bf((x1 * c + x2 * sn) * scq);
          obase[d + 32] = f2bf((x2 * c - x1 * sn) * scq);
        }
      }
  } else {
    // V: transpose 64x64 (rows=s, cols=d) -> vt[b][kv][d][s] via LDS
    const int kv = hh - 20;
    u16* tw = &TT[w][0];
#pragma unroll
    for (int mi = 0; mi < 4; mi++)
#pragma unroll
      for (int ni = 0; ni < 4; ni++)
#pragma unroll
        for (int rg = 0; rg < 4; rg++)
          tw[(ni * 16 + lc) * 66 + mi * 16 + lg * 4 + rg] = f2bf(acc[mi][ni][rg]);
    asm volatile("s_waitcnt lgkmcnt(0)" ::: "memory");
    __builtin_amdgcn_sched_barrier(0);
    const int r0 = bm + wr * 64;
    const int s0 = r0 & (SEQ - 1), b = r0 >> 11;
    u16* vbase = vt + (size_t)(b * NKV + kv) * 64 * SEQ + s0 + lane;
#pragma unroll 4
    for (int dd = 0; dd < 64; dd++)
      vbase[(size_t)dd * SEQ] = tw[dd * 66 + lane];
  }
}

// ---------------- fused gate+up GEMM (r12 v1, best measured): 256x128, BK=32 ----------------
__global__ __launch_bounds__(512, 2) void gateup_kernel(
    const u16* __restrict__ A, const u16* __restrict__ Bg,
    const u16* __restrict__ Bu, u16* __restrict__ outb) {
  const int K = 1024, N = 4096;
  __shared__ u16 SA[2][256 * 32];
  __shared__ u16 SG[2][128 * 32];
  __shared__ u16 SU[2][128 * 32];
  const int tid = threadIdx.x, lane = tid & 63, w = tid >> 6;  // 8 waves
  const int wr = w >> 1, wc = w & 1;
  const int lg = lane >> 4, lc = lane & 15;

  // bijective XCD map: 512 blocks = 16 m-blocks x 32 n-blocks
  const int r8 = blockIdx.x & 7, j = blockIdx.x >> 3;  // j: 0..63
  const int bm = (((r8 >> 1) << 2) + (j & 3)) << 8;
  const int bn = ((r8 & 1) * 16 + (j >> 2)) << 7;

  const int srow = tid >> 2;
  const int scs = ((tid & 3) ^ (srow & 3)) * 8;  // u16
  const u16* gAs = A + (size_t)(bm + srow) * K + scs;
  const u16* gGs = Bg + (size_t)(bn + srow) * K + scs;
  const u16* gUs = Bu + (size_t)(bn + srow) * K + scs;

  f32x4 accG[4][4] = {}, accU[4][4] = {};

#define SGU(T_) do { int sl_ = (T_) & 1; size_t ko_ = (size_t)(T_) * 32; \
    GLDS(gAs + ko_,                   &SA[sl_][w * 512]); \
    GLDS(gAs + ko_ + (size_t)128 * K, &SA[sl_][4096 + w * 512]); \
    GLDS(gGs + ko_,                   &SG[sl_][w * 512]); \
    GLDS(gUs + ko_,                   &SU[sl_][w * 512]); } while (0)

  SGU(0);
  VMCNT0;
  __builtin_amdgcn_s_barrier();

  for (int t = 0; t < 32; ++t) {
    const u16* sa = &SA[t & 1][0];
    const u16* sg = &SG[t & 1][0];
    const u16* su = &SU[t & 1][0];
    const bool more = (t + 1 < 32);

    bf16x8 afr[4], gfr[4], ufr[4];
#pragma unroll
    for (int i = 0; i < 4; i++) {
      const int row = wr * 64 + i * 16 + lc;
      afr[i] = *reinterpret_cast<const bf16x8*>(
          &sa[row * 32 + ((lg ^ (lc & 3)) << 3)]);
    }
#pragma unroll
    for (int n = 0; n < 4; n++) {
      const int row = wc * 64 + n * 16 + lc;
      const int off = row * 32 + ((lg ^ (lc & 3)) << 3);
      gfr[n] = *reinterpret_cast<const bf16x8*>(&sg[off]);
      ufr[n] = *reinterpret_cast<const bf16x8*>(&su[off]);
    }
    if (more) SGU(t + 1);
    __builtin_amdgcn_s_setprio(1);
#pragma unroll
    for (int i = 0; i < 4; i++)
#pragma unroll
      for (int n = 0; n < 4; n++) {
        accG[i][n] = __builtin_amdgcn_mfma_f32_16x16x32_bf16(afr[i], gfr[n], accG[i][n], 0, 0, 0);
        accU[i][n] = __builtin_amdgcn_mfma_f32_16x16x32_bf16(afr[i], ufr[n], accU[i][n], 0, 0, 0);
      }
    __builtin_amdgcn_s_setprio(0);
    VMCNT0;
    __builtin_amdgcn_s_barrier();
  }
#undef SGU

#pragma unroll
  for (int mi = 0; mi < 4; mi++)
#pragma unroll
    for (int ni = 0; ni < 4; ni++)
#pragma unroll
      for (int rg = 0; rg < 4; rg++) {
        const int row = bm + wr * 64 + mi * 16 + lg * 4 + rg;
        const int col = bn + wc * 64 + ni * 16 + lc;
        const float g = accG[mi][ni][rg];
        const float u = accU[mi][ni][rg];
        outb[(size_t)row * N + col] = f2bf((g / (1.0f + __expf(-g))) * u);
      }
}

// ---------------- Flash attention v4 (best measured): 8 waves, folded strips {j, 15-j} ----------------
__global__ __launch_bounds__(512, 1) void attn_kernel(
    const u16* __restrict__ qr, const u16* __restrict__ kr,
    const u16* __restrict__ vt, u16* __restrict__ out) {
  __shared__ u16 Ks[2][64 * 64];   // [key][d], swizzled
  __shared__ u16 Vs[2][64 * 64];   // [d][key], swizzled
  __shared__ u16 Ps[8][32 * 64];   // per-wave P[q][key], swizzled

  const int n = blockIdx.x;                 // 256 blocks
  const int g = n & 7;                      // b*4+kvh
  const int b = g >> 2, kvh = g & 3;
  const int h = kvh * 4 + ((n >> 3) & 3);
  const int j = n >> 5;                     // 0..7

  const int tid = threadIdx.x;
  const int lane = tid & 63, w = tid >> 6;  // 8 waves
  const int lg = lane >> 4, lc = lane & 15;
  const int lc7 = lc & 7;

  const int isH = (w ^ (w >> 2)) & 1;       // SIMD w&3 gets one light + one heavy
  const int strip = isH ? (15 - j) : j;     // 128-row q strip
  const int q0w = strip * 128 + (w >> 1) * 32;
  const int nt = 2 * (15 - j) + 2;          // tiles needed by heavy strip (18..32)

  bf16x8 qf[2][2];
  {
    const u16* qp = qr + ((size_t)(b * NH + h) * SEQ + q0w + lc) * 64 + lg * 8;
#pragma unroll
    for (int qt = 0; qt < 2; qt++) {
      qf[qt][0] = *reinterpret_cast<const bf16x8*>(qp + qt * 16 * 64);
      qf[qt][1] = *reinterpret_cast<const bf16x8*>(qp + qt * 16 * 64 + 32);
    }
  }
  VMCNT0;  // drain Q loads so in-loop vmcnt counting sees only GLDS

  const int srow = lane >> 3;                      // 0..7
  const int scw = ((lane & 7) ^ srow) << 3;        // pre-swizzled col (u16)
  const u16* ksrc = kr + (size_t)(b * NKV + kvh) * SEQ * 64 + (size_t)(w * 8 + srow) * 64 + scw;
  const u16* vsrc = vt + ((size_t)(b * NKV + kvh) * 64 + w * 8 + srow) * SEQ + scw;
  u16* Pw = &Ps[w][0];

#define STAGEA(bufi, t) do { \
    GLDS(ksrc + (size_t)(t) * 64 * 64, &Ks[bufi][(w * 8) * 64]); \
    GLDS(vsrc + (size_t)(t) * 64,      &Vs[bufi][(w * 8) * 64]); \
  } while (0)

  STAGEA(0, 0);

  float mm[2] = {-1e30f, -1e30f}, ll[2] = {0.0f, 0.0f};
  f32x4 oacc[2][4] = {};

  int buf = 0;
  for (int t = 0; t < nt; ++t) {
    if (t + 1 < nt) {
      STAGEA(buf ^ 1, t + 1);
      asm volatile("s_waitcnt vmcnt(2)" ::: "memory");
    } else {
      VMCNT0;
    }
    __builtin_amdgcn_s_barrier();
    __builtin_amdgcn_sched_barrier(0);

    const int c0 = t * 64;
    if (c0 <= q0w + 31) {
      bf16x8 kf[4][2];
#pragma unroll
      for (int ni = 0; ni < 4; ni++) {
        const int row = ni * 16 + lc;
#pragma unroll
        for (int hf = 0; hf < 2; hf++)
          kf[ni][hf] = *reinterpret_cast<const bf16x8*>(
              &Ks[buf][row * 64 + ((((hf * 64 + lg * 16)) ^ (lc7 << 4)) >> 1)]);
      }
      f32x4 sc[4][2] = {};
      __builtin_amdgcn_s_setprio(1);
#pragma unroll
      for (int ni = 0; ni < 4; ni++)
#pragma unroll
        for (int qt = 0; qt < 2; qt++) {
          sc[ni][qt] = __builtin_amdgcn_mfma_f32_16x16x32_bf16(kf[ni][0], qf[qt][0], sc[ni][qt], 0, 0, 0);
          sc[ni][qt] = __builtin_amdgcn_mfma_f32_16x16x32_bf16(kf[ni][1], qf[qt][1], sc[ni][qt], 0, 0, 0);
        }
      __builtin_amdgcn_s_setprio(0);
      bf16x8 vf[4][2];
#pragma unroll
      for (int dt = 0; dt < 4; dt++) {
        const int row = dt * 16 + lc;
#pragma unroll
        for (int ks = 0; ks < 2; ks++)
          vf[dt][ks] = *reinterpret_cast<const bf16x8*>(
              &Vs[buf][row * 64 + (((ks * 64 + lg * 16) ^ (lc7 << 4)) >> 1)]);
      }
      if (c0 + 63 > q0w) {
#pragma unroll
        for (int qt = 0; qt < 2; qt++) {
          const int q = q0w + qt * 16 + lc;
#pragma unroll
          for (int ni = 0; ni < 4; ni++)
#pragma unroll
            for (int rg = 0; rg < 4; rg++)
              if (c0 + ni * 16 + lg * 4 + rg > q) sc[ni][qt][rg] = -1e30f;
        }
      }
      float mx[2];
#pragma unroll
      for (int qt = 0; qt < 2; qt++) {
        float v = -1e30f;
#pragma unroll
        for (int ni = 0; ni < 4; ni++)
#pragma unroll
          for (int rg = 0; rg < 4; rg++) v = fmaxf(v, sc[ni][qt][rg]);
        v = fmaxf(v, __shfl_xor(v, 16));
        v = fmaxf(v, __shfl_xor(v, 32));
        mx[qt] = v;
      }
      if (!__all(mx[0] - mm[0] <= 11.5f && mx[1] - mm[1] <= 11.5f)) {
        float al[2];
#pragma unroll
        for (int qt = 0; qt < 2; qt++) {
          float mn = fmaxf(mm[qt], mx[qt]);
          al[qt] = exp2f(mm[qt] - mn);
          mm[qt] = mn;
          ll[qt] *= al[qt];
        }
#pragma unroll
        for (int qt = 0; qt < 2; qt++)
#pragma unroll
          for (int rg = 0; rg < 4; rg++) {
            float a = __shfl(al[qt], lg * 4 + rg);
#pragma unroll
            for (int dt = 0; dt < 4; dt++) oacc[qt][dt][rg] *= a;
          }
      }
#pragma unroll
      for (int qt = 0; qt < 2; qt++) {
        float rs = 0.0f;
#pragma unroll
        for (int ni = 0; ni < 4; ni++)
#pragma unroll
          for (int rg = 0; rg < 4; rg++) {
            float p = exp2f(sc[ni][qt][rg] - mm[qt]);
            sc[ni][qt][rg] = p;
            rs += p;
          }
        rs += __shfl_xor(rs, 16);
        rs += __shfl_xor(rs, 32);
        ll[qt] += rs;
      }
#pragma unroll
      for (int qt = 0; qt < 2; qt++)
#pragma unroll
        for (int ni = 0; ni < 4; ni++) {
          ushort4 pk;
          pk.x = f2bf(sc[ni][qt][0]);
          pk.y = f2bf(sc[ni][qt][1]);
          pk.z = f2bf(sc[ni][qt][2]);
          pk.w = f2bf(sc[ni][qt][3]);
          *reinterpret_cast<ushort4*>(
              &Pw[(qt * 16 + lc) * 64 + (((ni * 32 + lg * 8) ^ (lc7 << 4)) >> 1)]) = pk;
        }
      __builtin_amdgcn_s_setprio(1);
#pragma unroll
      for (int qt = 0; qt < 2; qt++)
#pragma unroll
        for (int ks = 0; ks < 2; ks++) {
          bf16x8 pa = *reinterpret_cast<const bf16x8*>(
              &Pw[(qt * 16 + lc) * 64 + (((ks * 64 + lg * 16) ^ (lc7 << 4)) >> 1)]);
#pragma unroll
          for (int dt = 0; dt < 4; dt++)
            oacc[qt][dt] = __builtin_amdgcn_mfma_f32_16x16x32_bf16(pa, vf[dt][ks], oacc[qt][dt], 0, 0, 0);
        }
      __builtin_amdgcn_s_setprio(0);
    }
    asm volatile("s_waitcnt lgkmcnt(0)" ::: "memory");
    __builtin_amdgcn_s_barrier();
    __builtin_amdgcn_sched_barrier(0);
    buf ^= 1;
  }
#undef STAGEA

#pragma unroll
  for (int qt = 0; qt < 2; qt++) {
    const float li = 1.0f / ll[qt];
#pragma unroll
    for (int rg = 0; rg < 4; rg++) {
      float liq = __shfl(li, lg * 4 + rg);
      int q = q0w + qt * 16 + lg * 4 + rg;
      u16* orow = out + (size_t)(b * SEQ + q) * 1024 + h * 64 + lc;
#pragma unroll
      for (int dt = 0; dt < 4; dt++)
        orow[dt * 16] = f2bf(oacc[qt][dt][rg] * liq);
    }
  }
}

extern "C" void kernel_launch(void* const* d_in, const int* in_sizes, int n_in,
                              void* d_out, int out_size, void* d_ws, size_t ws_size,
                              hipStream_t stream) {
  const float* x = (const float*)d_in[0];
  const float* w_norm1 = (const float*)d_in[1];
  const float* wq = (const float*)d_in[2];
  const float* wk = (const float*)d_in[3];
  const float* wv = (const float*)d_in[4];
  const float* wo = (const float*)d_in[5];
  const float* attn_scale = (const float*)d_in[6];
  const float* w_norm2 = (const float*)d_in[7];
  const float* wg = (const float*)d_in[8];
  const float* wu = (const float*)d_in[9];
  const float* wd = (const float*)d_in[10];
  const float* mlp_scale = (const float*)d_in[11];
  const float* cosb = (const float*)d_in[12];
  const float* sinb = (const float*)d_in[13];
  float* out = (float*)d_out;

  char* ws = (char*)d_ws;
  u16* wqkv_t = (u16*)(ws + 0);            // 1536x1024 bf16
  u16* wo_t = (u16*)(ws + 3145728);        // 1024x1024 bf16
  u16* wg_t = (u16*)(ws + 5242880);        // 4096x1024 bf16
  u16* wu_t = (u16*)(ws + 13631488);
  u16* wd_t = (u16*)(ws + 22020096);       // 1024x4096 bf16
  u16* xn = (u16*)(ws + 30408704);         // 4096x1024 bf16 (reused for xn2)
  u16* attn_o = (u16*)(ws + 38797312);     // 4096x1024 bf16
  float* x1 = (float*)(ws + 47185920);     // 4096x1024 f32
  u16* q_rope = (u16*)(ws + 63963136);     // 2*16*2048*64 bf16
  u16* k_rope = (u16*)(ws + 72351744);     // 2*4*2048*64 bf16
  u16* vt = (u16*)(ws + 74448896);         // 2*4*64*2048 bf16
  u16* hbuf = (u16*)(ws + 63963136);       // alias (rope bufs dead in FFN phase)

  dim3 tb(256);
  transpose_cast_kernel<<<dim3(32, 32), tb, 0, stream>>>(wq, wqkv_t, 1024, 1024);
  transpose_cast_kernel<<<dim3(8, 32), tb, 0, stream>>>(wk, wqkv_t + (size_t)1024 * 1024, 1024, 256);
  transpose_cast_kernel<<<dim3(8, 32), tb, 0, stream>>>(wv, wqkv_t + (size_t)1280 * 1024, 1024, 256);
  transpose_cast_kernel<<<dim3(32, 32), tb, 0, stream>>>(wo, wo_t, 1024, 1024);
  transpose_cast_kernel<<<dim3(128, 32), tb, 0, stream>>>(wg, wg_t, 1024, 4096);
  transpose_cast_kernel<<<dim3(128, 32), tb, 0, stream>>>(wu, wu_t, 1024, 4096);
  transpose_cast_kernel<<<dim3(32, 128), tb, 0, stream>>>(wd, wd_t, 4096, 1024);

  rmsnorm_kernel<<<4096, tb, 0, stream>>>(x, w_norm1, xn);
  qkvrope_kernel<<<dim3(384), tb, 0, stream>>>(xn, wqkv_t, cosb, sinb, q_rope, k_rope, vt);
  attn_kernel<<<256, dim3(512), 0, stream>>>(q_rope, k_rope, vt, attn_o);
  gemmB<1><<<dim3(256), tb, 0, stream>>>(attn_o, wo_t, 4096, 1024, 1024, x1, x, attn_scale, nullptr);
  rmsnorm_kernel<<<4096, tb, 0, stream>>>(x1, w_norm2, xn);
  gateup_kernel<<<dim3(512), dim3(512), 0, stream>>>(xn, wg_t, wu_t, hbuf);
  gemmB<1><<<dim3(256), tb, 0, stream>>>(hbuf, wd_t, 4096, 1024, 4096, out, x1, mlp_scale, nullptr);
}

// Round 16
// 267.202 us; speedup vs baseline: 1.0098x; 1.0002x over previous
//
#include <hip/hip_runtime.h>
#include <hip/hip_bf16.h>
#include <cstdint>

typedef unsigned short u16;
typedef unsigned int u32;
typedef __attribute__((ext_vector_type(4))) float f32x4;
typedef __attribute__((ext_vector_type(8))) __bf16 bf16x8;

#define NH 16
#define NKV 4
#define SEQ 2048
#define NTOK 4096

__device__ inline u16 f2bf(float f) {
  return __builtin_bit_cast(u16, __float2bfloat16(f));
}
__device__ inline float bf2f(u16 u) {
  return __bfloat162float(__builtin_bit_cast(__hip_bfloat16, u));
}

#define GLDS(gp, lp) __builtin_amdgcn_global_load_lds( \
    (__attribute__((address_space(1))) void*)(gp), \
    (__attribute__((address_space(3))) void*)(lp), 16, 0, 0)

#define VMCNT0 asm volatile("s_waitcnt vmcnt(0)" ::: "memory")

// ---------------- RMSNorm (f32 in, bf16 out) ----------------
__global__ __launch_bounds__(256) void rmsnorm_kernel(
    const float* __restrict__ x, const float* __restrict__ w,
    u16* __restrict__ out) {
  int row = blockIdx.x;
  int tid = threadIdx.x;
  const float4 v = reinterpret_cast<const float4*>(x + (size_t)row * 1024)[tid];
  float ss = v.x * v.x + v.y * v.y + v.z * v.z + v.w * v.w;
#pragma unroll
  for (int off = 32; off; off >>= 1) ss += __shfl_xor(ss, off);
  __shared__ float red[4];
  int lane = tid & 63, wid = tid >> 6;
  if (lane == 0) red[wid] = ss;
  __syncthreads();
  float tot = red[0] + red[1] + red[2] + red[3];
  float r = rsqrtf(tot * (1.0f / 1024.0f) + 1e-6f);
  const float4 wv = reinterpret_cast<const float4*>(w)[tid];
  ushort4 o;
  o.x = f2bf(v.x * r * wv.x);
  o.y = f2bf(v.y * r * wv.y);
  o.z = f2bf(v.z * r * wv.z);
  o.w = f2bf(v.w * r * wv.w);
  reinterpret_cast<ushort4*>(out + (size_t)row * 1024)[tid] = o;
}

// ---------------- weight transpose + cast: src[K][N] f32 -> dst[N][K] bf16 ----------------
__global__ __launch_bounds__(256) void transpose_cast_kernel(
    const float* __restrict__ src, u16* __restrict__ dst, int K, int N) {
  __shared__ float tile[32][33];
  int n0 = blockIdx.x * 32, k0 = blockIdx.y * 32;
  int tx = threadIdx.x & 31, ty = threadIdx.x >> 5;  // ty: 0..7
#pragma unroll
  for (int i = 0; i < 4; i++)
    tile[ty + i * 8][tx] = src[(size_t)(k0 + ty + i * 8) * N + n0 + tx];
  __syncthreads();
#pragma unroll
  for (int i = 0; i < 4; i++)
    dst[(size_t)(n0 + ty + i * 8) * K + k0 + tx] = f2bf(tile[tx][ty + i * 8]);
}

// Shared epilogue
template <int EP>
__device__ inline void epi_store(float v, size_t idx, int col,
                                 float* __restrict__ outf,
                                 const float* __restrict__ res,
                                 const float* __restrict__ scale,
                                 u16* __restrict__ outb) {
  if (EP == 0) {
    outf[idx] = v;
  } else if (EP == 1) {
    outf[idx] = res[idx] + v * scale[col];
  } else if (EP == 2) {
    outb[idx] = f2bf(v / (1.0f + __expf(-v)));
  } else {
    outb[idx] = f2bf(bf2f(outb[idx]) * v);
  }
}

// ---------------- gemmB: 128x128 tile, BK=64, 4 waves ----------------
template <int EP>
__global__ __launch_bounds__(256, 1) void gemmB(
    const u16* __restrict__ A, const u16* __restrict__ Bt,
    int M, int N, int K,
    float* __restrict__ outf, const float* __restrict__ res,
    const float* __restrict__ scale, u16* __restrict__ outb) {
  __shared__ u16 SA[2][128 * 64];
  __shared__ u16 SB[2][128 * 64];
  const int tid = threadIdx.x, lane = tid & 63, w = tid >> 6;  // 0..3
  const int wr = w >> 1, wc = w & 1;
  const int lg = lane >> 4, lc = lane & 15, cx = lc & 7;

  const int r8 = blockIdx.x & 7, j = blockIdx.x >> 3;
  const int bm = ((r8 << 2) + (j & 3)) << 7;   // M=4096: 32 m-blocks, 4 per XCD
  const int bn = (j >> 2) << 7;

  const int swrow = lane >> 3;
  const int swcol = (lane & 7) ^ swrow;
  const u16* gA = A + (size_t)(bm + w * 32 + swrow) * K + swcol * 8;
  const u16* gB = Bt + (size_t)(bn + w * 32 + swrow) * K + swcol * 8;

  const int NT = K >> 6;
  f32x4 acc[4][4] = {};

#define SG2(T_) do { int sl_ = (T_) & 1; size_t ko_ = (size_t)(T_) * 64; \
    GLDS(gA + ko_,                   &SA[sl_][(w * 32) * 64]); \
    GLDS(gA + ko_ + (size_t)8 * K,   &SA[sl_][(w * 32 + 8) * 64]); \
    GLDS(gA + ko_ + (size_t)16 * K,  &SA[sl_][(w * 32 + 16) * 64]); \
    GLDS(gA + ko_ + (size_t)24 * K,  &SA[sl_][(w * 32 + 24) * 64]); \
    GLDS(gB + ko_,                   &SB[sl_][(w * 32) * 64]); \
    GLDS(gB + ko_ + (size_t)8 * K,   &SB[sl_][(w * 32 + 8) * 64]); \
    GLDS(gB + ko_ + (size_t)16 * K,  &SB[sl_][(w * 32 + 16) * 64]); \
    GLDS(gB + ko_ + (size_t)24 * K,  &SB[sl_][(w * 32 + 24) * 64]); } while (0)

  SG2(0);
  VMCNT0;
  __builtin_amdgcn_s_barrier();

  for (int t = 0; t < NT; ++t) {
    const u16* sa = &SA[t & 1][0];
    const u16* sb = &SB[t & 1][0];
    const bool more = (t + 1 < NT);

    bf16x8 bfr[4][2], afr[4][2];
#pragma unroll
    for (int n = 0; n < 4; n++) {
      const int row = wc * 64 + n * 16 + lc;
#pragma unroll
      for (int ks = 0; ks < 2; ks++)
        bfr[n][ks] = *reinterpret_cast<const bf16x8*>(
            &sb[row * 64 + ((((ks << 2) | lg) ^ cx) << 3)]);
    }
#pragma unroll
    for (int i = 0; i < 4; i++) {
      const int row = wr * 64 + i * 16 + lc;
#pragma unroll
      for (int ks = 0; ks < 2; ks++)
        afr[i][ks] = *reinterpret_cast<const bf16x8*>(
            &sa[row * 64 + ((((ks << 2) | lg) ^ cx) << 3)]);
    }
    if (more) SG2(t + 1);
    __builtin_amdgcn_s_setprio(1);
#pragma unroll
    for (int i = 0; i < 4; i++)
#pragma unroll
      for (int n = 0; n < 4; n++) {
        acc[i][n] = __builtin_amdgcn_mfma_f32_16x16x32_bf16(afr[i][0], bfr[n][0], acc[i][n], 0, 0, 0);
        acc[i][n] = __builtin_amdgcn_mfma_f32_16x16x32_bf16(afr[i][1], bfr[n][1], acc[i][n], 0, 0, 0);
      }
    __builtin_amdgcn_s_setprio(0);
    VMCNT0;
    __builtin_amdgcn_s_barrier();
  }
#undef SG2

#pragma unroll
  for (int mi = 0; mi < 4; mi++)
#pragma unroll
    for (int ni = 0; ni < 4; ni++)
#pragma unroll
      for (int rg = 0; rg < 4; rg++) {
        const int row = bm + wr * 64 + mi * 16 + lg * 4 + rg;
        const int col = bn + wc * 64 + ni * 16 + lc;
        epi_store<EP>(acc[mi][ni][rg], (size_t)row * N + col, col, outf, res, scale, outb);
      }
}

// ---------------- QKV GEMM with fused RoPE + V-transpose epilogue ----------------
// gemmB engine (128x128, BK=64, 4 waves). N=1536: n-blocks 0-7 Q, 8-9 K, 10-11 V.
// Each 64-col wave half is head-aligned; rope pair (d, d+32) = acc[.][ni]/acc[.][ni+2].
__global__ __launch_bounds__(256, 1) void qkvrope_kernel(
    const u16* __restrict__ A, const u16* __restrict__ Bt,
    const float* __restrict__ cosb, const float* __restrict__ sinb,
    u16* __restrict__ qr, u16* __restrict__ kr, u16* __restrict__ vt) {
  const int N = 1536, K = 1024, NT = 16;
  __shared__ u16 SA[2][128 * 64];
  __shared__ u16 SB[2][128 * 64];
  __shared__ u16 TT[4][64 * 66];
  const int tid = threadIdx.x, lane = tid & 63, w = tid >> 6;
  const int wr = w >> 1, wc = w & 1;
  const int lg = lane >> 4, lc = lane & 15, cx = lc & 7;

  // 384 blocks = 32 m-blocks x 12 n-blocks, XCD digit on m
  const int r8 = blockIdx.x & 7, j = blockIdx.x >> 3;  // j: 0..47
  const int bm = ((r8 << 2) + (j & 3)) << 7;
  const int bn = (j >> 2) << 7;

  const int swrow = lane >> 3;
  const int swcol = (lane & 7) ^ swrow;
  const u16* gA = A + (size_t)(bm + w * 32 + swrow) * K + swcol * 8;
  const u16* gB = Bt + (size_t)(bn + w * 32 + swrow) * K + swcol * 8;

  f32x4 acc[4][4] = {};

#define SG2(T_) do { int sl_ = (T_) & 1; size_t ko_ = (size_t)(T_) * 64; \
    GLDS(gA + ko_,                   &SA[sl_][(w * 32) * 64]); \
    GLDS(gA + ko_ + (size_t)8 * K,   &SA[sl_][(w * 32 + 8) * 64]); \
    GLDS(gA + ko_ + (size_t)16 * K,  &SA[sl_][(w * 32 + 16) * 64]); \
    GLDS(gA + ko_ + (size_t)24 * K,  &SA[sl_][(w * 32 + 24) * 64]); \
    GLDS(gB + ko_,                   &SB[sl_][(w * 32) * 64]); \
    GLDS(gB + ko_ + (size_t)8 * K,   &SB[sl_][(w * 32 + 8) * 64]); \
    GLDS(gB + ko_ + (size_t)16 * K,  &SB[sl_][(w * 32 + 16) * 64]); \
    GLDS(gB + ko_ + (size_t)24 * K,  &SB[sl_][(w * 32 + 24) * 64]); } while (0)

  SG2(0);
  VMCNT0;
  __builtin_amdgcn_s_barrier();

  for (int t = 0; t < NT; ++t) {
    const u16* sa = &SA[t & 1][0];
    const u16* sb = &SB[t & 1][0];
    const bool more = (t + 1 < NT);

    bf16x8 bfr[4][2], afr[4][2];
#pragma unroll
    for (int n = 0; n < 4; n++) {
      const int row = wc * 64 + n * 16 + lc;
#pragma unroll
      for (int ks = 0; ks < 2; ks++)
        bfr[n][ks] = *reinterpret_cast<const bf16x8*>(
            &sb[row * 64 + ((((ks << 2) | lg) ^ cx) << 3)]);
    }
#pragma unroll
    for (int i = 0; i < 4; i++) {
      const int row = wr * 64 + i * 16 + lc;
#pragma unroll
      for (int ks = 0; ks < 2; ks++)
        afr[i][ks] = *reinterpret_cast<const bf16x8*>(
            &sa[row * 64 + ((((ks << 2) | lg) ^ cx) << 3)]);
    }
    if (more) SG2(t + 1);
    __builtin_amdgcn_s_setprio(1);
#pragma unroll
    for (int i = 0; i < 4; i++)
#pragma unroll
      for (int n = 0; n < 4; n++) {
        acc[i][n] = __builtin_amdgcn_mfma_f32_16x16x32_bf16(afr[i][0], bfr[n][0], acc[i][n], 0, 0, 0);
        acc[i][n] = __builtin_amdgcn_mfma_f32_16x16x32_bf16(afr[i][1], bfr[n][1], acc[i][n], 0, 0, 0);
      }
    __builtin_amdgcn_s_setprio(0);
    VMCNT0;
    __builtin_amdgcn_s_barrier();
  }
#undef SG2

  const int colbase = bn + wc * 64;
  const int hh = colbase >> 6;  // 0..23
  const float QSC = 0.18033688011112042f;  // 0.125 * log2(e)

  if (hh < 20) {
    // Q (rope, scaled) or K (rope, unscaled)
    const bool isQ = (hh < 16);
    const int head = isQ ? hh : hh - 16;
    u16* dst = isQ ? qr : kr;
    const int hstride = isQ ? NH : NKV;
    const float scq = isQ ? QSC : 1.0f;
#pragma unroll
    for (int mi = 0; mi < 4; mi++)
#pragma unroll
      for (int rg = 0; rg < 4; rg++) {
        const int row = bm + wr * 64 + mi * 16 + lg * 4 + rg;
        const int s = row & (SEQ - 1), b = row >> 11;
        u16* obase = dst + ((size_t)(b * hstride + head) * SEQ + s) * 64;
#pragma unroll
        for (int ni = 0; ni < 2; ni++) {
          const int d = ni * 16 + lc;
          const float c = cosb[s * 32 + d];
          const float sn = sinb[s * 32 + d];
          const float x1 = acc[mi][ni][rg];
          const float x2 = acc[mi][ni + 2][rg];
          obase[d] = f2bf((x1 * c + x2 * sn) * scq);
          obase[d + 32] = f2bf((x2 * c - x1 * sn) * scq);
        }
      }
  } else {
    // V: transpose 64x64 (rows=s, cols=d) -> vt[b][kv][d][s] via LDS
    const int kv = hh - 20;
    u16* tw = &TT[w][0];
#pragma unroll
    for (int mi = 0; mi < 4; mi++)
#pragma unroll
      for (int ni = 0; ni < 4; ni++)
#pragma unroll
        for (int rg = 0; rg < 4; rg++)
          tw[(ni * 16 + lc) * 66 + mi * 16 + lg * 4 + rg] = f2bf(acc[mi][ni][rg]);
    asm volatile("s_waitcnt lgkmcnt(0)" ::: "memory");
    __builtin_amdgcn_sched_barrier(0);
    const int r0 = bm + wr * 64;
    const int s0 = r0 & (SEQ - 1), b = r0 >> 11;
    u16* vbase = vt + (size_t)(b * NKV + kv) * 64 * SEQ + s0 + lane;
#pragma unroll 4
    for (int dd = 0; dd < 64; dd++)
      vbase[(size_t)dd * SEQ] = tw[dd * 66 + lane];
  }
}

// ---------------- fused gate+up GEMM (r12 v1, best measured): 256x128, BK=32 ----------------
__global__ __launch_bounds__(512, 2) void gateup_kernel(
    const u16* __restrict__ A, const u16* __restrict__ Bg,
    const u16* __restrict__ Bu, u16* __restrict__ outb) {
  const int K = 1024, N = 4096;
  __shared__ u16 SA[2][256 * 32];
  __shared__ u16 SG[2][128 * 32];
  __shared__ u16 SU[2][128 * 32];
  const int tid = threadIdx.x, lane = tid & 63, w = tid >> 6;  // 8 waves
  const int wr = w >> 1, wc = w & 1;
  const int lg = lane >> 4, lc = lane & 15;

  // bijective XCD map: 512 blocks = 16 m-blocks x 32 n-blocks
  const int r8 = blockIdx.x & 7, j = blockIdx.x >> 3;  // j: 0..63
  const int bm = (((r8 >> 1) << 2) + (j & 3)) << 8;
  const int bn = ((r8 & 1) * 16 + (j >> 2)) << 7;

  const int srow = tid >> 2;
  const int scs = ((tid & 3) ^ (srow & 3)) * 8;  // u16
  const u16* gAs = A + (size_t)(bm + srow) * K + scs;
  const u16* gGs = Bg + (size_t)(bn + srow) * K + scs;
  const u16* gUs = Bu + (size_t)(bn + srow) * K + scs;

  f32x4 accG[4][4] = {}, accU[4][4] = {};

#define SGU(T_) do { int sl_ = (T_) & 1; size_t ko_ = (size_t)(T_) * 32; \
    GLDS(gAs + ko_,                   &SA[sl_][w * 512]); \
    GLDS(gAs + ko_ + (size_t)128 * K, &SA[sl_][4096 + w * 512]); \
    GLDS(gGs + ko_,                   &SG[sl_][w * 512]); \
    GLDS(gUs + ko_,                   &SU[sl_][w * 512]); } while (0)

  SGU(0);
  VMCNT0;
  __builtin_amdgcn_s_barrier();

  for (int t = 0; t < 32; ++t) {
    const u16* sa = &SA[t & 1][0];
    const u16* sg = &SG[t & 1][0];
    const u16* su = &SU[t & 1][0];
    const bool more = (t + 1 < 32);

    bf16x8 afr[4], gfr[4], ufr[4];
#pragma unroll
    for (int i = 0; i < 4; i++) {
      const int row = wr * 64 + i * 16 + lc;
      afr[i] = *reinterpret_cast<const bf16x8*>(
          &sa[row * 32 + ((lg ^ (lc & 3)) << 3)]);
    }
#pragma unroll
    for (int n = 0; n < 4; n++) {
      const int row = wc * 64 + n * 16 + lc;
      const int off = row * 32 + ((lg ^ (lc & 3)) << 3);
      gfr[n] = *reinterpret_cast<const bf16x8*>(&sg[off]);
      ufr[n] = *reinterpret_cast<const bf16x8*>(&su[off]);
    }
    if (more) SGU(t + 1);
    __builtin_amdgcn_s_setprio(1);
#pragma unroll
    for (int i = 0; i < 4; i++)
#pragma unroll
      for (int n = 0; n < 4; n++) {
        accG[i][n] = __builtin_amdgcn_mfma_f32_16x16x32_bf16(afr[i], gfr[n], accG[i][n], 0, 0, 0);
        accU[i][n] = __builtin_amdgcn_mfma_f32_16x16x32_bf16(afr[i], ufr[n], accU[i][n], 0, 0, 0);
      }
    __builtin_amdgcn_s_setprio(0);
    VMCNT0;
    __builtin_amdgcn_s_barrier();
  }
#undef SGU

#pragma unroll
  for (int mi = 0; mi < 4; mi++)
#pragma unroll
    for (int ni = 0; ni < 4; ni++)
#pragma unroll
      for (int rg = 0; rg < 4; rg++) {
        const int row = bm + wr * 64 + mi * 16 + lg * 4 + rg;
        const int col = bn + wc * 64 + ni * 16 + lc;
        const float g = accG[mi][ni][rg];
        const float u = accU[mi][ni][rg];
        outb[(size_t)row * N + col] = f2bf((g / (1.0f + __expf(-g))) * u);
      }
}

// ---------------- Flash attention v4 (best measured): 8 waves, folded strips {j, 15-j} ----------------
__global__ __launch_bounds__(512, 1) void attn_kernel(
    const u16* __restrict__ qr, const u16* __restrict__ kr,
    const u16* __restrict__ vt, u16* __restrict__ out) {
  __shared__ u16 Ks[2][64 * 64];   // [key][d], swizzled
  __shared__ u16 Vs[2][64 * 64];   // [d][key], swizzled
  __shared__ u16 Ps[8][32 * 64];   // per-wave P[q][key], swizzled

  const int n = blockIdx.x;                 // 256 blocks
  const int g = n & 7;                      // b*4+kvh
  const int b = g >> 2, kvh = g & 3;
  const int h = kvh * 4 + ((n >> 3) & 3);
  const int j = n >> 5;                     // 0..7

  const int tid = threadIdx.x;
  const int lane = tid & 63, w = tid >> 6;  // 8 waves
  const int lg = lane >> 4, lc = lane & 15;
  const int lc7 = lc & 7;

  const int isH = (w ^ (w >> 2)) & 1;       // SIMD w&3 gets one light + one heavy
  const int strip = isH ? (15 - j) : j;     // 128-row q strip
  const int q0w = strip * 128 + (w >> 1) * 32;
  const int nt = 2 * (15 - j) + 2;          // tiles needed by heavy strip (18..32)

  bf16x8 qf[2][2];
  {
    const u16* qp = qr + ((size_t)(b * NH + h) * SEQ + q0w + lc) * 64 + lg * 8;
#pragma unroll
    for (int qt = 0; qt < 2; qt++) {
      qf[qt][0] = *reinterpret_cast<const bf16x8*>(qp + qt * 16 * 64);
      qf[qt][1] = *reinterpret_cast<const bf16x8*>(qp + qt * 16 * 64 + 32);
    }
  }
  VMCNT0;  // drain Q loads so in-loop vmcnt counting sees only GLDS

  const int srow = lane >> 3;                      // 0..7
  const int scw = ((lane & 7) ^ srow) << 3;        // pre-swizzled col (u16)
  const u16* ksrc = kr + (size_t)(b * NKV + kvh) * SEQ * 64 + (size_t)(w * 8 + srow) * 64 + scw;
  const u16* vsrc = vt + ((size_t)(b * NKV + kvh) * 64 + w * 8 + srow) * SEQ + scw;
  u16* Pw = &Ps[w][0];

#define STAGEA(bufi, t) do { \
    GLDS(ksrc + (size_t)(t) * 64 * 64, &Ks[bufi][(w * 8) * 64]); \
    GLDS(vsrc + (size_t)(t) * 64,      &Vs[bufi][(w * 8) * 64]); \
  } while (0)

  STAGEA(0, 0);

  float mm[2] = {-1e30f, -1e30f}, ll[2] = {0.0f, 0.0f};
  f32x4 oacc[2][4] = {};

  int buf = 0;
  for (int t = 0; t < nt; ++t) {
    if (t + 1 < nt) {
      STAGEA(buf ^ 1, t + 1);
      asm volatile("s_waitcnt vmcnt(2)" ::: "memory");
    } else {
      VMCNT0;
    }
    __builtin_amdgcn_s_barrier();
    __builtin_amdgcn_sched_barrier(0);

    const int c0 = t * 64;
    if (c0 <= q0w + 31) {
      bf16x8 kf[4][2];
#pragma unroll
      for (int ni = 0; ni < 4; ni++) {
        const int row = ni * 16 + lc;
#pragma unroll
        for (int hf = 0; hf < 2; hf++)
          kf[ni][hf] = *reinterpret_cast<const bf16x8*>(
              &Ks[buf][row * 64 + ((((hf * 64 + lg * 16)) ^ (lc7 << 4)) >> 1)]);
      }
      f32x4 sc[4][2] = {};
      __builtin_amdgcn_s_setprio(1);
#pragma unroll
      for (int ni = 0; ni < 4; ni++)
#pragma unroll
        for (int qt = 0; qt < 2; qt++) {
          sc[ni][qt] = __builtin_amdgcn_mfma_f32_16x16x32_bf16(kf[ni][0], qf[qt][0], sc[ni][qt], 0, 0, 0);
          sc[ni][qt] = __builtin_amdgcn_mfma_f32_16x16x32_bf16(kf[ni][1], qf[qt][1], sc[ni][qt], 0, 0, 0);
        }
      __builtin_amdgcn_s_setprio(0);
      bf16x8 vf[4][2];
#pragma unroll
      for (int dt = 0; dt < 4; dt++) {
        const int row = dt * 16 + lc;
#pragma unroll
        for (int ks = 0; ks < 2; ks++)
          vf[dt][ks] = *reinterpret_cast<const bf16x8*>(
              &Vs[buf][row * 64 + (((ks * 64 + lg * 16) ^ (lc7 << 4)) >> 1)]);
      }
      if (c0 + 63 > q0w) {
#pragma unroll
        for (int qt = 0; qt < 2; qt++) {
          const int q = q0w + qt * 16 + lc;
#pragma unroll
          for (int ni = 0; ni < 4; ni++)
#pragma unroll
            for (int rg = 0; rg < 4; rg++)
              if (c0 + ni * 16 + lg * 4 + rg > q) sc[ni][qt][rg] = -1e30f;
        }
      }
      float mx[2];
#pragma unroll
      for (int qt = 0; qt < 2; qt++) {
        float v = -1e30f;
#pragma unroll
        for (int ni = 0; ni < 4; ni++)
#pragma unroll
          for (int rg = 0; rg < 4; rg++) v = fmaxf(v, sc[ni][qt][rg]);
        v = fmaxf(v, __shfl_xor(v, 16));
        v = fmaxf(v, __shfl_xor(v, 32));
        mx[qt] = v;
      }
      if (!__all(mx[0] - mm[0] <= 11.5f && mx[1] - mm[1] <= 11.5f)) {
        float al[2];
#pragma unroll
        for (int qt = 0; qt < 2; qt++) {
          float mn = fmaxf(mm[qt], mx[qt]);
          al[qt] = exp2f(mm[qt] - mn);
          mm[qt] = mn;
          ll[qt] *= al[qt];
        }
#pragma unroll
        for (int qt = 0; qt < 2; qt++)
#pragma unroll
          for (int rg = 0; rg < 4; rg++) {
            float a = __shfl(al[qt], lg * 4 + rg);
#pragma unroll
            for (int dt = 0; dt < 4; dt++) oacc[qt][dt][rg] *= a;
          }
      }
#pragma unroll
      for (int qt = 0; qt < 2; qt++) {
        float rs = 0.0f;
#pragma unroll
        for (int ni = 0; ni < 4; ni++)
#pragma unroll
          for (int rg = 0; rg < 4; rg++) {
            float p = exp2f(sc[ni][qt][rg] - mm[qt]);
            sc[ni][qt][rg] = p;
            rs += p;
          }
        rs += __shfl_xor(rs, 16);
        rs += __shfl_xor(rs, 32);
        ll[qt] += rs;
      }
#pragma unroll
      for (int qt = 0; qt < 2; qt++)
#pragma unroll
        for (int ni = 0; ni < 4; ni++) {
          ushort4 pk;
          pk.x = f2bf(sc[ni][qt][0]);
          pk.y = f2bf(sc[ni][qt][1]);
          pk.z = f2bf(sc[ni][qt][2]);
          pk.w = f2bf(sc[ni][qt][3]);
          *reinterpret_cast<ushort4*>(
              &Pw[(qt * 16 + lc) * 64 + (((ni * 32 + lg * 8) ^ (lc7 << 4)) >> 1)]) = pk;
        }
      __builtin_amdgcn_s_setprio(1);
#pragma unroll
      for (int qt = 0; qt < 2; qt++)
#pragma unroll
        for (int ks = 0; ks < 2; ks++) {
          bf16x8 pa = *reinterpret_cast<const bf16x8*>(
              &Pw[(qt * 16 + lc) * 64 + (((ks * 64 + lg * 16) ^ (lc7 << 4)) >> 1)]);
#pragma unroll
          for (int dt = 0; dt < 4; dt++)
            oacc[qt][dt] = __builtin_amdgcn_mfma_f32_16x16x32_bf16(pa, vf[dt][ks], oacc[qt][dt], 0, 0, 0);
        }
      __builtin_amdgcn_s_setprio(0);
    }
    asm volatile("s_waitcnt lgkmcnt(0)" ::: "memory");
    __builtin_amdgcn_s_barrier();
    __builtin_amdgcn_sched_barrier(0);
    buf ^= 1;
  }
#undef STAGEA

#pragma unroll
  for (int qt = 0; qt < 2; qt++) {
    const float li = 1.0f / ll[qt];
#pragma unroll
    for (int rg = 0; rg < 4; rg++) {
      float liq = __shfl(li, lg * 4 + rg);
      int q = q0w + qt * 16 + lg * 4 + rg;
      u16* orow = out + (size_t)(b * SEQ + q) * 1024 + h * 64 + lc;
#pragma unroll
      for (int dt = 0; dt < 4; dt++)
        orow[dt * 16] = f2bf(oacc[qt][dt][rg] * liq);
    }
  }
}

extern "C" void kernel_launch(void* const* d_in, const int* in_sizes, int n_in,
                              void* d_out, int out_size, void* d_ws, size_t ws_size,
                              hipStream_t stream) {
  const float* x = (const float*)d_in[0];
  const float* w_norm1 = (const float*)d_in[1];
  const float* wq = (const float*)d_in[2];
  const float* wk = (const float*)d_in[3];
  const float* wv = (const float*)d_in[4];
  const float* wo = (const float*)d_in[5];
  const float* attn_scale = (const float*)d_in[6];
  const float* w_norm2 = (const float*)d_in[7];
  const float* wg = (const float*)d_in[8];
  const float* wu = (const float*)d_in[9];
  const float* wd = (const float*)d_in[10];
  const float* mlp_scale = (const float*)d_in[11];
  const float* cosb = (const float*)d_in[12];
  const float* sinb = (const float*)d_in[13];
  float* out = (float*)d_out;

  char* ws = (char*)d_ws;
  u16* wqkv_t = (u16*)(ws + 0);            // 1536x1024 bf16
  u16* wo_t = (u16*)(ws + 3145728);        // 1024x1024 bf16
  u16* wg_t = (u16*)(ws + 5242880);        // 4096x1024 bf16
  u16* wu_t = (u16*)(ws + 13631488);
  u16* wd_t = (u16*)(ws + 22020096);       // 1024x4096 bf16
  u16* xn = (u16*)(ws + 30408704);         // 4096x1024 bf16 (reused for xn2)
  u16* attn_o = (u16*)(ws + 38797312);     // 4096x1024 bf16
  float* x1 = (float*)(ws + 47185920);     // 4096x1024 f32
  u16* q_rope = (u16*)(ws + 63963136);     // 2*16*2048*64 bf16
  u16* k_rope = (u16*)(ws + 72351744);     // 2*4*2048*64 bf16
  u16* vt = (u16*)(ws + 74448896);         // 2*4*64*2048 bf16
  u16* hbuf = (u16*)(ws + 63963136);       // alias (rope bufs dead in FFN phase)

  dim3 tb(256);
  transpose_cast_kernel<<<dim3(32, 32), tb, 0, stream>>>(wq, wqkv_t, 1024, 1024);
  transpose_cast_kernel<<<dim3(8, 32), tb, 0, stream>>>(wk, wqkv_t + (size_t)1024 * 1024, 1024, 256);
  transpose_cast_kernel<<<dim3(8, 32), tb, 0, stream>>>(wv, wqkv_t + (size_t)1280 * 1024, 1024, 256);
  transpose_cast_kernel<<<dim3(32, 32), tb, 0, stream>>>(wo, wo_t, 1024, 1024);
  transpose_cast_kernel<<<dim3(128, 32), tb, 0, stream>>>(wg, wg_t, 1024, 4096);
  transpose_cast_kernel<<<dim3(128, 32), tb, 0, stream>>>(wu, wu_t, 1024, 4096);
  transpose_cast_kernel<<<dim3(32, 128), tb, 0, stream>>>(wd, wd_t, 4096, 1024);

  rmsnorm_kernel<<<4096, tb, 0, stream>>>(x, w_norm1, xn);
  qkvrope_kernel<<<dim3(384), tb, 0, stream>>>(xn, wqkv_t, cosb, sinb, q_rope, k_rope, vt);
  attn_kernel<<<256, dim3(512), 0, stream>>>(q_rope, k_rope, vt, attn_o);
  gemmB<1><<<dim3(256), tb, 0, stream>>>(attn_o, wo_t, 4096, 1024, 1024, x1, x, attn_scale, nullptr);
  rmsnorm_kernel<<<4096, tb, 0, stream>>>(x1, w_norm2, xn);
  gateup_kernel<<<dim3(512), dim3(512), 0, stream>>>(xn, wg_t, wu_t, hbuf);
  gemmB<1><<<dim3(256), tb, 0, stream>>>(hbuf, wd_t, 4096, 1024, 4096, out, x1, mlp_scale, nullptr);
}